// Round 1
// 1000.142 us; speedup vs baseline: 1.3319x; 1.3319x over previous
//
#include <hip/hip_runtime.h>

typedef unsigned int u32;
typedef unsigned short u16;
typedef u16 u16x8 __attribute__((ext_vector_type(8)));
typedef u16 u16x4 __attribute__((ext_vector_type(4)));
typedef __bf16 bf16x8 __attribute__((ext_vector_type(8)));
typedef __bf16 bf16x4v __attribute__((ext_vector_type(4)));
typedef float f32x4 __attribute__((ext_vector_type(4)));
typedef float f32x2 __attribute__((ext_vector_type(2)));

#define B_SZ 32
#define S_SZ 128
#define T_SZ 127
#define DK 128
#define SKILL 256
#define SHALF 128  /* skills per block after 2-way split */
#define RL 136     /* hS row pitch (u16): 128 + 8 pad */
#define PP 68      /* part row pitch (f32): 64 + 4 pad */

__device__ __forceinline__ u16x4 cvt4(f32x4 v) {
    return __builtin_bit_cast(u16x4, __builtin_convertvector(v, bf16x4v));
}
__device__ __forceinline__ u16x8 cvt8(f32x4 a, f32x4 b) {
    u16x4 x = cvt4(a), y = cvt4(b);
    u16x8 r;
    r[0]=x[0]; r[1]=x[1]; r[2]=x[2]; r[3]=x[3];
    r[4]=y[0]; r[5]=y[1]; r[6]=y[2]; r[7]=y[3];
    return r;
}
__device__ __forceinline__ u16 bfu(float x) {
    return __builtin_bit_cast(u16, (__bf16)x);
}
__device__ __forceinline__ float sigm(float x) {
    float e = __builtin_amdgcn_exp2f(-1.44269504f * x);
    return __builtin_amdgcn_rcpf(1.f + e);
}
__device__ __forceinline__ float tanh_f(float x) {
    float e = __builtin_amdgcn_exp2f(-2.88539008f * x);
    return 2.f * __builtin_amdgcn_rcpf(1.f + e) - 1.f;
}
__device__ __forceinline__ f32x4 mfma16(u16x8 a, u16x8 bb, f32x4 c) {
    return __builtin_amdgcn_mfma_f32_16x16x32_bf16(
        __builtin_bit_cast(bf16x8, a), __builtin_bit_cast(bf16x8, bb), c, 0, 0, 0);
}

// ---------------------------------------------------------------------------
// Kernel A: le[b,t,:] = W1 @ [ex | at | ans] + b1  (unchanged, proven)
// ---------------------------------------------------------------------------
__global__ __launch_bounds__(128) void k_le(
    const int* __restrict__ eid, const int* __restrict__ atime,
    const int* __restrict__ ansv, const float* __restrict__ ex_t,
    const float* __restrict__ at_t, const float* __restrict__ W1,
    const float* __restrict__ b1, float* __restrict__ le_ws)
{
    int t = blockIdx.x, bq = blockIdx.y, d = threadIdx.x;
    __shared__ float exS[128], atS[128];
    for (int bb = 0; bb < 4; ++bb) {
        int b = bq * 4 + bb;
        int e = eid[b * S_SZ + t];
        int a = atime[b * S_SZ + t];
        float av = (float)ansv[b * S_SZ + t];
        exS[d] = ex_t[e * DK + d];
        atS[d] = at_t[a * DK + d];
        __syncthreads();
        const float* wr = W1 + d * 384;
        float acc = b1[d];
        float wsum = 0.f;
        #pragma unroll 8
        for (int k4 = 0; k4 < 32; ++k4) {
            f32x4 w = *(const f32x4*)(wr + 4 * k4);
            acc += w[0] * exS[4 * k4] + w[1] * exS[4 * k4 + 1]
                 + w[2] * exS[4 * k4 + 2] + w[3] * exS[4 * k4 + 3];
        }
        #pragma unroll 8
        for (int k4 = 32; k4 < 64; ++k4) {
            f32x4 w = *(const f32x4*)(wr + 4 * k4);
            acc += w[0] * atS[4 * k4 - 128] + w[1] * atS[4 * k4 - 127]
                 + w[2] * atS[4 * k4 - 126] + w[3] * atS[4 * k4 - 125];
        }
        #pragma unroll 8
        for (int k4 = 64; k4 < 96; ++k4) {
            f32x4 w = *(const f32x4*)(wr + 4 * k4);
            wsum += w[0] + w[1] + w[2] + w[3];
        }
        acc += av * wsum;
        le_ws[(b * T_SZ + t) * DK + d] = acc;
        __syncthreads();
    }
}

// ---------------------------------------------------------------------------
// Kernel B: input-only gate pre-activations (unchanged, proven)
// ---------------------------------------------------------------------------
__global__ __launch_bounds__(128) void k_pre(
    const int* __restrict__ itime, const float* __restrict__ it_t,
    const float* __restrict__ Wl, const float* __restrict__ blv,
    const float* __restrict__ Wg, const float* __restrict__ bgv,
    const float* __restrict__ Wf, const float* __restrict__ bfv,
    const float* __restrict__ le_ws,
    float* __restrict__ PRE_l, float* __restrict__ PRE_g, float* __restrict__ PRE_f)
{
    int t = blockIdx.x, bq = blockIdx.y, o = threadIdx.x;
    __shared__ float lp[128], lc[128], itS[128];
    for (int bb = 0; bb < 4; ++bb) {
        int b = bq * 4 + bb;
        int iv = itime[b * S_SZ + t + 1];
        itS[o] = it_t[iv * DK + o];
        lc[o] = le_ws[(b * T_SZ + t) * DK + o];
        lp[o] = (t == 0) ? 0.f : le_ws[(b * T_SZ + t - 1) * DK + o];
        __syncthreads();
        const float* wl = Wl + o * 512;
        const float* wg = Wg + o * 512;
        float al = blv[o], ag = bgv[o];
        #pragma unroll 8
        for (int k4 = 0; k4 < 32; ++k4) {
            f32x4 w  = *(const f32x4*)(wl + 4 * k4);
            f32x4 w2 = *(const f32x4*)(wg + 4 * k4);
            #pragma unroll
            for (int j = 0; j < 4; ++j) {
                float x = lp[4 * k4 + j];
                al += w[j] * x; ag += w2[j] * x;
            }
        }
        #pragma unroll 8
        for (int k4 = 32; k4 < 64; ++k4) {
            f32x4 w  = *(const f32x4*)(wl + 4 * k4);
            f32x4 w2 = *(const f32x4*)(wg + 4 * k4);
            #pragma unroll
            for (int j = 0; j < 4; ++j) {
                float x = itS[4 * k4 - 128 + j];
                al += w[j] * x; ag += w2[j] * x;
            }
        }
        #pragma unroll 8
        for (int k4 = 64; k4 < 96; ++k4) {
            f32x4 w  = *(const f32x4*)(wl + 4 * k4);
            f32x4 w2 = *(const f32x4*)(wg + 4 * k4);
            #pragma unroll
            for (int j = 0; j < 4; ++j) {
                float x = lc[4 * k4 - 256 + j];
                al += w[j] * x; ag += w2[j] * x;
            }
        }
        float af = bfv[o];
        const float* wf = Wf + o * 384 + 256;
        #pragma unroll 8
        for (int k4 = 0; k4 < 32; ++k4) {
            f32x4 w = *(const f32x4*)(wf + 4 * k4);
            af += w[0] * itS[4 * k4] + w[1] * itS[4 * k4 + 1]
                + w[2] * itS[4 * k4 + 2] + w[3] * itS[4 * k4 + 3];
        }
        size_t idx = (size_t)(b * T_SZ + t) * DK + o;
        PRE_l[idx] = al;
        PRE_g[idx] = ag;
        PRE_f[idx] = af;
        __syncthreads();
    }
}

// ---------------------------------------------------------------------------
// Kernel C: sequential scan, 2-way skill-split: grid (B,2), block (b,sh) owns
// skills 128*sh..128*sh+127.  Per-step cross-block exchange of the 128-float
// h~ partial via L3 (agent-scope sc1 atomics + per-wave monotonic flags).
// z/LG/c are d-indexed and computed redundantly in both blocks.
// Zf (f-gate MFMA) for step t+1 is computed in the publish->spin gap, where
// hS is stable (also removes the old Zf-h2 vs partner-update race).
// ---------------------------------------------------------------------------
__global__ __launch_bounds__(512, 1) void k_main(
    const int* __restrict__ eid, const float* __restrict__ qmat,
    const float* __restrict__ Wl, const float* __restrict__ Wg,
    const float* __restrict__ Wf, const float* __restrict__ h0,
    const float* __restrict__ PRE_l, const float* __restrict__ PRE_g,
    const float* __restrict__ PRE_f, float* __restrict__ ht_ws,
    float* __restrict__ xbuf, int* __restrict__ flags)
{
    extern __shared__ char smem[];
    u16*   hS   = (u16*)smem;                    // 128*136*2 = 34816
    float* part = (float*)(smem + 34816);        // 128*68*4  = 34816 -> 69632
    u16*   htbf = (u16*)(smem + 69632);          // hi[128], lo[128] -> 70144
    u16*   LGb  = (u16*)(smem + 70144);          // hi[128], lo[128] -> 70656
    float* LGf  = (float*)(smem + 70656);        // 512 -> 71168
    float* cS   = (float*)(smem + 71168);        // 512 -> 71680

    const int b    = blockIdx.x;
    const int sh   = blockIdx.y;     // which skill half this block owns
    const int po   = 1 - sh;         // partner
    const int tid  = threadIdx.x;
    const int w    = tid >> 6;
    const int lane = tid & 63;
    const int quad = lane >> 4;
    const int l4   = lane & 15;
    const int ih   = w & 1;          // d-half
    const int jh   = w >> 1;         // 32-skill quarter within this block's half

    float* xb  = xbuf  + b * 512;    // [sh][slot][128] f32
    int*   flg = flags + b * 16;     // [sh][wave] monotonic step counters

    // ---- persistent A-frags ----
    // Wf1 (Zf): m = 64ih+16mt+l4, k = 32kt+quad*8+j
    u16x8 afr[4][4];
    #pragma unroll
    for (int mt = 0; mt < 4; ++mt)
        #pragma unroll
        for (int kt = 0; kt < 4; ++kt) {
            const float* p = Wf + (64 * ih + 16 * mt + l4) * 384 + 32 * kt + quad * 8;
            afr[mt][kt] = cvt8(*(const f32x4*)p, *(const f32x4*)(p + 4));
        }
    // z stacked [Wl4;Wg4] row-interleaved (redundant per block)
    u16x8 azf[2][4];
    #pragma unroll
    for (int mt = 0; mt < 2; ++mt)
        #pragma unroll
        for (int kt = 0; kt < 4; ++kt) {
            int d = 16 * w + 8 * mt + (l4 >> 1);
            const float* base = (l4 & 1) ? Wg : Wl;
            const float* p = base + d * 512 + 384 + 32 * kt + quad * 8;
            azf[mt][kt] = cvt8(*(const f32x4*)p, *(const f32x4*)(p + 4));
        }
    // Wf2 (c): m = 16w+l4 (redundant per block)
    u16x8 acf[4];
    #pragma unroll
    for (int kt = 0; kt < 4; ++kt) {
        const float* p = Wf + (16 * w + l4) * 384 + 128 + 32 * kt + quad * 8;
        acf[kt] = cvt8(*(const f32x4*)p, *(const f32x4*)(p + 4));
    }

    // ---- h0 (own half only) -> fp32 regs + bf16 LDS mirror ----
    f32x4 hreg[4][2];   // [mt][nt]: h[64ih+16mt+quad*4+r][32jh+16nt+l4]
    #pragma unroll
    for (int mt = 0; mt < 4; ++mt) {
        int d0 = 64 * ih + 16 * mt + quad * 4;
        #pragma unroll
        for (int nt = 0; nt < 2; ++nt) {
            int s = 32 * jh + 16 * nt + l4;
            f32x4 hv = *(const f32x4*)(h0 + (SHALF * sh + s) * DK + d0);
            hreg[mt][nt] = hv;
            *(u16x4*)(hS + s * RL + d0) = cvt4(hv);
        }
    }

    // ---- kv[t=0] (own half) ----
    float kvt[2];
    {
        int e0 = eid[b * S_SZ];
        #pragma unroll
        for (int nt = 0; nt < 2; ++nt)
            kvt[nt] = qmat[e0 * SKILL + SHALF * sh + 32 * jh + 16 * nt + l4];
    }

    f32x4 accF[4][2];   // Zf accumulators, carried across iterations

    // ---- prologue: partial h~0, exchange, Zf(t=0) ----
    {
        float htp[16];
        #pragma unroll
        for (int v2 = 0; v2 < 16; ++v2) htp[v2] = 0.f;
        #pragma unroll
        for (int nt = 0; nt < 2; ++nt)
            #pragma unroll
            for (int mt = 0; mt < 4; ++mt)
                #pragma unroll
                for (int r = 0; r < 4; ++r)
                    htp[mt * 4 + r] += kvt[nt] * hreg[mt][nt][r];
        #pragma unroll
        for (int mt = 0; mt < 4; ++mt)
            #pragma unroll
            for (int r = 0; r < 4; ++r)
                part[(64 * ih + 16 * mt + quad * 4 + r) * PP + jh * 16 + l4] = htp[mt * 4 + r];
        __syncthreads();   // hS + part ready
        int d = tid >> 2, kq = tid & 3;
        const float* pp = part + d * PP + kq * 16;
        float v = 0.f;
        #pragma unroll
        for (int i4 = 0; i4 < 4; ++i4) {
            f32x4 x = *(const f32x4*)(pp + 4 * i4);
            v += x[0] + x[1] + x[2] + x[3];
        }
        v += __shfl_xor(v, 1, 64);
        v += __shfl_xor(v, 2, 64);
        // publish my half-partial (slot 1, seq 1)
        if (kq == 0)
            __hip_atomic_store(xb + (sh * 2 + 1) * 128 + d, v,
                               __ATOMIC_RELAXED, __HIP_MEMORY_SCOPE_AGENT);
        asm volatile("s_waitcnt vmcnt(0)" ::: "memory");
        if (lane == 0)
            __hip_atomic_store(flg + sh * 8 + w, 1,
                               __ATOMIC_RELAXED, __HIP_MEMORY_SCOPE_AGENT);
        // Zf for t=0 (hS stable) overlaps partner's publish
        #pragma unroll
        for (int mt = 0; mt < 4; ++mt)
            #pragma unroll
            for (int n2 = 0; n2 < 2; ++n2)
                accF[mt][n2] = (f32x4){0.f, 0.f, 0.f, 0.f};
        #pragma unroll
        for (int n2 = 0; n2 < 2; ++n2) {
            const u16* bp = hS + (32 * jh + 16 * n2 + l4) * RL + quad * 8;
            u16x8 bfr[4];
            #pragma unroll
            for (int kt = 0; kt < 4; ++kt) bfr[kt] = *(const u16x8*)(bp + kt * 32);
            #pragma unroll
            for (int mt = 0; mt < 4; ++mt)
                #pragma unroll
                for (int kt = 0; kt < 4; ++kt)
                    accF[mt][n2] = mfma16(afr[mt][kt], bfr[kt], accF[mt][n2]);
        }
        if (lane == 0) {
            int spins = 0;
            while (__hip_atomic_load(flg + po * 8 + w,
                                     __ATOMIC_RELAXED, __HIP_MEMORY_SCOPE_AGENT) < 1) {
                __builtin_amdgcn_s_sleep(1);
                if (++spins > (1 << 20)) break;   // fail loud, never hang
            }
        }
        asm volatile("" ::: "memory");
        if (kq == 0) {
            float o = __hip_atomic_load(xb + (po * 2 + 1) * 128 + d,
                                        __ATOMIC_RELAXED, __HIP_MEMORY_SCOPE_AGENT);
            v += o;
            float hf = (float)(__bf16)v;
            htbf[d] = bfu(v);
            htbf[128 + d] = bfu(v - hf);
        }
        __syncthreads();   // TOP: h~0 ready
    }

    for (int t = 0; t < T_SZ; ++t) {
        const size_t tb = (size_t)(b * T_SZ + t) * DK;
        // ---- prefetch (global) ----
        int en = eid[b * S_SZ + t + 1];
        float kvn[2];
        #pragma unroll
        for (int nt = 0; nt < 2; ++nt)
            kvn[nt] = qmat[en * SKILL + SHALF * sh + 32 * jh + 16 * nt + l4];
        f32x2 pl[2], pg[2];
        #pragma unroll
        for (int mt = 0; mt < 2; ++mt) {
            int d0 = 16 * w + 8 * mt + 2 * quad;
            pl[mt] = *(const f32x2*)(PRE_l + tb + d0);
            pg[mt] = *(const f32x2*)(PRE_g + tb + d0);
        }
        f32x4 pf = *(const f32x4*)(PRE_f + tb + 16 * w + quad * 4);

        // ---- z-MFMA: [Wl4;Wg4] @ h~ (hi + lo) ----
        f32x4 accZ[2];
        accZ[0] = (f32x4){0.f, 0.f, 0.f, 0.f};
        accZ[1] = (f32x4){0.f, 0.f, 0.f, 0.f};
        #pragma unroll
        for (int kt = 0; kt < 4; ++kt) {
            u16x8 bh = *(const u16x8*)(htbf + 32 * kt + quad * 8);
            u16x8 bl = *(const u16x8*)(htbf + 128 + 32 * kt + quad * 8);
            #pragma unroll
            for (int mt = 0; mt < 2; ++mt) {
                accZ[mt] = mfma16(azf[mt][kt], bh, accZ[mt]);
                accZ[mt] = mfma16(azf[mt][kt], bl, accZ[mt]);
            }
        }
        // ---- z epilogue -> LG ----
        #pragma unroll
        for (int mt = 0; mt < 2; ++mt) {
            u32 hpack = 0, lpack = 0;
            f32x2 fpack;
            #pragma unroll
            for (int rp = 0; rp < 2; ++rp) {
                float zl = accZ[mt][2 * rp] + pl[mt][rp];
                float zg = accZ[mt][2 * rp + 1] + pg[mt][rp];
                float LGv = sigm(zg) * (tanh_f(zl) + 1.f) * 0.5f;
                float hif = (float)(__bf16)LGv;
                hpack |= ((u32)bfu(LGv)) << (16 * rp);
                lpack |= ((u32)bfu(LGv - hif)) << (16 * rp);
                fpack[rp] = LGv;
            }
            if (l4 == 0) {
                int d0 = 16 * w + 8 * mt + 2 * quad;
                *(u32*)(LGb + d0) = hpack;
                *(u32*)(LGb + 128 + d0) = lpack;
                *(f32x2*)(LGf + d0) = fpack;
            }
        }
        __syncthreads();   // B: LG ready

        // ---- c-MFMA: Wf2 @ LG (hi+lo) ----
        {
            f32x4 accC = (f32x4){0.f, 0.f, 0.f, 0.f};
            #pragma unroll
            for (int kt = 0; kt < 4; ++kt) {
                u16x8 bh = *(const u16x8*)(LGb + 32 * kt + quad * 8);
                u16x8 bl = *(const u16x8*)(LGb + 128 + 32 * kt + quad * 8);
                accC = mfma16(acf[kt], bh, accC);
                accC = mfma16(acf[kt], bl, accC);
            }
            accC += pf;
            if (l4 == 0) *(f32x4*)(cS + 16 * w + quad * 4) = accC;
        }
        __syncthreads();   // C: c ready

        // ---- update (both 16-skill groups; accF from previous gap) ----
        float htp[16];
        #pragma unroll
        for (int v2 = 0; v2 < 16; ++v2) htp[v2] = 0.f;
        #pragma unroll
        for (int mt = 0; mt < 4; ++mt) {
            int d0 = 64 * ih + 16 * mt + quad * 4;
            f32x4 lg = *(const f32x4*)(LGf + d0);
            f32x4 cc = *(const f32x4*)(cS + d0);
            #pragma unroll
            for (int n2 = 0; n2 < 2; ++n2) {
                int s = 32 * jh + 16 * n2 + l4;
                f32x4 hv;
                #pragma unroll
                for (int r = 0; r < 4; ++r) {
                    float f = sigm(accF[mt][n2][r] + cc[r]);
                    float hn = kvt[n2] * lg[r] + f * hreg[mt][n2][r];
                    hreg[mt][n2][r] = hn;
                    htp[mt * 4 + r] += kvn[n2] * hn;
                    hv[r] = hn;
                }
                *(u16x4*)(hS + s * RL + d0) = cvt4(hv);
            }
        }
        // ---- h~ partial scatter ----
        #pragma unroll
        for (int mt = 0; mt < 4; ++mt)
            #pragma unroll
            for (int r = 0; r < 4; ++r)
                part[(64 * ih + 16 * mt + quad * 4 + r) * PP + jh * 16 + l4] = htp[mt * 4 + r];
        kvt[0] = kvn[0];
        kvt[1] = kvn[1];
        __syncthreads();   // E: partials + hS(t+1) ready

        // ---- reduce -> my half-partial; exchange; Zf(t+1) in the gap ----
        {
            int d = tid >> 2, kq = tid & 3;
            const float* pp = part + d * PP + kq * 16;
            float v = 0.f;
            #pragma unroll
            for (int i4 = 0; i4 < 4; ++i4) {
                f32x4 x = *(const f32x4*)(pp + 4 * i4);
                v += x[0] + x[1] + x[2] + x[3];
            }
            v += __shfl_xor(v, 1, 64);
            v += __shfl_xor(v, 2, 64);
            int slot = t & 1;          // seq = t+2 -> slot (t+2)&1 = t&1
            if (kq == 0)
                __hip_atomic_store(xb + (sh * 2 + slot) * 128 + d, v,
                                   __ATOMIC_RELAXED, __HIP_MEMORY_SCOPE_AGENT);
            asm volatile("s_waitcnt vmcnt(0)" ::: "memory");
            if (lane == 0)
                __hip_atomic_store(flg + sh * 8 + w, t + 2,
                                   __ATOMIC_RELAXED, __HIP_MEMORY_SCOPE_AGENT);
            // Zf for t+1 (hS stable until next [C]) hides exchange latency
            #pragma unroll
            for (int mt = 0; mt < 4; ++mt)
                #pragma unroll
                for (int n2 = 0; n2 < 2; ++n2)
                    accF[mt][n2] = (f32x4){0.f, 0.f, 0.f, 0.f};
            #pragma unroll
            for (int n2 = 0; n2 < 2; ++n2) {
                const u16* bp = hS + (32 * jh + 16 * n2 + l4) * RL + quad * 8;
                u16x8 bfr[4];
                #pragma unroll
                for (int kt = 0; kt < 4; ++kt) bfr[kt] = *(const u16x8*)(bp + kt * 32);
                #pragma unroll
                for (int mt = 0; mt < 4; ++mt)
                    #pragma unroll
                    for (int kt = 0; kt < 4; ++kt)
                        accF[mt][n2] = mfma16(afr[mt][kt], bfr[kt], accF[mt][n2]);
            }
            if (lane == 0) {
                int spins = 0;
                while (__hip_atomic_load(flg + po * 8 + w,
                                         __ATOMIC_RELAXED, __HIP_MEMORY_SCOPE_AGENT) < t + 2) {
                    __builtin_amdgcn_s_sleep(1);
                    if (++spins > (1 << 20)) break;
                }
            }
            asm volatile("" ::: "memory");
            if (kq == 0) {
                float o = __hip_atomic_load(xb + (po * 2 + slot) * 128 + d,
                                            __ATOMIC_RELAXED, __HIP_MEMORY_SCOPE_AGENT);
                v += o;
                float hf = (float)(__bf16)v;
                htbf[d] = bfu(v);
                htbf[128 + d] = bfu(v - hf);
                if (sh == 0) ht_ws[tb + d] = v;
            }
        }
        __syncthreads();   // TOP: h~ ready
    }
}

// ---------------------------------------------------------------------------
// Kernel D: pred (unchanged, proven)
// ---------------------------------------------------------------------------
__global__ __launch_bounds__(128) void k_pred(
    const int* __restrict__ eid, const float* __restrict__ ex_t,
    const float* __restrict__ Wp, const float* __restrict__ bpv,
    const float* __restrict__ ht_ws, float* __restrict__ out)
{
    int t = blockIdx.x, bq = blockIdx.y, d = threadIdx.x;
    __shared__ float exS[128], htS[128];
    for (int bb = 0; bb < 4; ++bb) {
        int b = bq * 4 + bb;
        int e = eid[b * S_SZ + t + 1];
        exS[d] = ex_t[e * DK + d];
        htS[d] = ht_ws[(size_t)(b * T_SZ + t) * DK + d];
        __syncthreads();
        const float* wr = Wp + d * 256;
        float z = bpv[d];
        #pragma unroll 8
        for (int k4 = 0; k4 < 32; ++k4) {
            f32x4 w = *(const f32x4*)(wr + 4 * k4);
            z += w[0] * exS[4 * k4] + w[1] * exS[4 * k4 + 1]
               + w[2] * exS[4 * k4 + 2] + w[3] * exS[4 * k4 + 3];
        }
        #pragma unroll 8
        for (int k4 = 32; k4 < 64; ++k4) {
            f32x4 w = *(const f32x4*)(wr + 4 * k4);
            z += w[0] * htS[4 * k4 - 128] + w[1] * htS[4 * k4 - 127]
               + w[2] * htS[4 * k4 - 126] + w[3] * htS[4 * k4 - 125];
        }
        out[(size_t)(b * T_SZ + t) * DK + d] = sigm(z);
        __syncthreads();
    }
}

extern "C" void kernel_launch(void* const* d_in, const int* in_sizes, int n_in,
                              void* d_out, int out_size, void* d_ws, size_t ws_size,
                              hipStream_t stream) {
    const int* eid     = (const int*)d_in[0];
    const int* atime   = (const int*)d_in[1];
    const int* itime   = (const int*)d_in[2];
    const int* ansv    = (const int*)d_in[3];
    const float* qmat  = (const float*)d_in[4];
    const float* ex_t  = (const float*)d_in[5];
    const float* at_t  = (const float*)d_in[6];
    const float* it_t  = (const float*)d_in[7];
    const float* W1    = (const float*)d_in[8];
    const float* b1    = (const float*)d_in[9];
    const float* Wl    = (const float*)d_in[10];
    const float* blv   = (const float*)d_in[11];
    const float* Wg    = (const float*)d_in[12];
    const float* bgv   = (const float*)d_in[13];
    const float* Wf    = (const float*)d_in[14];
    const float* bfv   = (const float*)d_in[15];
    const float* Wp    = (const float*)d_in[16];
    const float* bpv   = (const float*)d_in[17];
    const float* h0    = (const float*)d_in[18];
    float* out = (float*)d_out;

    const size_t SZ = (size_t)B_SZ * T_SZ * DK;
    float* wsf   = (float*)d_ws;
    float* le_ws = wsf;
    float* PRE_l = wsf + SZ;
    float* PRE_g = wsf + 2 * SZ;
    float* PRE_f = wsf + 3 * SZ;
    float* ht_ws = wsf + 4 * SZ;
    // le_ws is dead after k_pre -> reuse its head for the exchange buffers.
    float* xbuf  = le_ws;                      // 32*2*2*128 f32 = 64 KiB
    int*   flags = (int*)(le_ws + 16384);      // 32*16 ints = 2 KiB

    // LDS actually used: 71680; request 84 KiB to pin 1 block/CU.
    hipFuncSetAttribute((const void*)k_main,
                        hipFuncAttributeMaxDynamicSharedMemorySize, 86016);

    dim3 g(T_SZ, 8);
    k_le  <<<g, 128, 0, stream>>>(eid, atime, ansv, ex_t, at_t, W1, b1, le_ws);
    k_pre <<<g, 128, 0, stream>>>(itime, it_t, Wl, blv, Wg, bgv, Wf, bfv,
                                  le_ws, PRE_l, PRE_g, PRE_f);
    // stream-ordered after k_pre (le data dead), before k_main: flags = 0
    hipMemsetAsync(flags, 0, 32 * 16 * sizeof(int), stream);
    k_main<<<dim3(B_SZ, 2), 512, 86016, stream>>>(eid, qmat, Wl, Wg, Wf, h0,
                                                  PRE_l, PRE_g, PRE_f, ht_ws,
                                                  xbuf, flags);
    k_pred<<<g, 128, 0, stream>>>(eid, ex_t, Wp, bpv, ht_ws, out);
}

// Round 2
// 771.336 us; speedup vs baseline: 1.7270x; 1.2966x over previous
//
#include <hip/hip_runtime.h>

typedef unsigned int u32;
typedef unsigned short u16;
typedef u16 u16x8 __attribute__((ext_vector_type(8)));
typedef u16 u16x4 __attribute__((ext_vector_type(4)));
typedef __bf16 bf16x8 __attribute__((ext_vector_type(8)));
typedef __bf16 bf16x4v __attribute__((ext_vector_type(4)));
typedef float f32x4 __attribute__((ext_vector_type(4)));
typedef float f32x2 __attribute__((ext_vector_type(2)));

#define B_SZ 32
#define S_SZ 128
#define T_SZ 127
#define DK 128
#define SKILL 256
#define SHALF 128  /* skills per block after 2-way split */
#define RL 136     /* hS row pitch (u16): 128 + 8 pad */
#define PP 68      /* part row pitch (f32): 64 + 4 pad */
#define NPAIR 16   /* (b,t) pairs per aux block; 4064 = 254*16 */

__device__ __forceinline__ u16x4 cvt4(f32x4 v) {
    return __builtin_bit_cast(u16x4, __builtin_convertvector(v, bf16x4v));
}
__device__ __forceinline__ u16x8 cvt8(f32x4 a, f32x4 b) {
    u16x4 x = cvt4(a), y = cvt4(b);
    u16x8 r;
    r[0]=x[0]; r[1]=x[1]; r[2]=x[2]; r[3]=x[3];
    r[4]=y[0]; r[5]=y[1]; r[6]=y[2]; r[7]=y[3];
    return r;
}
__device__ __forceinline__ u16 bfu(float x) {
    return __builtin_bit_cast(u16, (__bf16)x);
}
__device__ __forceinline__ float sigm(float x) {
    float e = __builtin_amdgcn_exp2f(-1.44269504f * x);
    return __builtin_amdgcn_rcpf(1.f + e);
}
__device__ __forceinline__ float tanh_f(float x) {
    float e = __builtin_amdgcn_exp2f(-2.88539008f * x);
    return 2.f * __builtin_amdgcn_rcpf(1.f + e) - 1.f;
}
__device__ __forceinline__ f32x4 mfma16(u16x8 a, u16x8 bb, f32x4 c) {
    return __builtin_amdgcn_mfma_f32_16x16x32_bf16(
        __builtin_bit_cast(bf16x8, a), __builtin_bit_cast(bf16x8, bb), c, 0, 0, 0);
}

// ---------------------------------------------------------------------------
// Kernel A (v2): le[p,:] = W1 @ [ex | at | ans] + b1.
// Weights read ONCE per block (k-outer / pair-inner), x staged in LDS and
// read with wave-uniform broadcast addresses. 254 blocks x 16 pairs.
// Accumulation order per output identical to v1 (ex, at, then av*wsum).
// ---------------------------------------------------------------------------
__global__ __launch_bounds__(256) void k_le(
    const int* __restrict__ eid, const int* __restrict__ atime,
    const int* __restrict__ ansv, const float* __restrict__ ex_t,
    const float* __restrict__ at_t, const float* __restrict__ W1,
    const float* __restrict__ b1, float* __restrict__ le_ws)
{
    __shared__ float xS[NPAIR * 256];   // [pair][0:128 ex | 128:256 at]
    __shared__ int   eS[NPAIR], aS[NPAIR];
    __shared__ float avS[NPAIR];
    const int tid = threadIdx.x;
    const int p0 = blockIdx.x * NPAIR;
    if (tid < NPAIR) {
        int p = p0 + tid;
        int b = p / T_SZ, t = p - b * T_SZ;
        eS[tid] = eid[b * S_SZ + t];
        aS[tid] = atime[b * S_SZ + t];
        avS[tid] = (float)ansv[b * S_SZ + t];
    }
    __syncthreads();
    #pragma unroll
    for (int it = 0; it < 4; ++it) {
        int f = it * 256 + tid;            // 1024 f32x4 chunks
        int pr = f >> 6, c = f & 63;
        const float* src = (c < 32) ? ex_t + eS[pr] * DK + 4 * c
                                    : at_t + aS[pr] * DK + 4 * (c - 32);
        *(f32x4*)(xS + pr * 256 + 4 * c) = *(const f32x4*)src;
    }
    __syncthreads();
    const int o = tid & 127, g = tid >> 7;
    const float* wr = W1 + o * 384;
    const float bias = b1[o];
    float acc[8];
    #pragma unroll
    for (int i = 0; i < 8; ++i) acc[i] = bias;
    #pragma unroll 2
    for (int k4 = 0; k4 < 64; ++k4) {
        f32x4 w = *(const f32x4*)(wr + 4 * k4);
        #pragma unroll
        for (int i = 0; i < 8; ++i) {
            f32x4 x = *(const f32x4*)(xS + (g * 8 + i) * 256 + 4 * k4);
            acc[i] += w[0] * x[0] + w[1] * x[1] + w[2] * x[2] + w[3] * x[3];
        }
    }
    float wsum = 0.f;
    #pragma unroll 4
    for (int k4 = 64; k4 < 96; ++k4) {
        f32x4 w = *(const f32x4*)(wr + 4 * k4);
        wsum += w[0] + w[1] + w[2] + w[3];
    }
    #pragma unroll
    for (int i = 0; i < 8; ++i) {
        int p = p0 + g * 8 + i;
        le_ws[p * DK + o] = acc[i] + avS[g * 8 + i] * wsum;
    }
}

// ---------------------------------------------------------------------------
// Kernel B (v2): gate pre-activations, same restructure.
// x = [lp | it | lc] (384), matches Wl/Wg col order 0:384; f-gate uses
// Wf cols 256:384 on the it slice. 254 blocks x 16 pairs.
// ---------------------------------------------------------------------------
__global__ __launch_bounds__(256) void k_pre(
    const int* __restrict__ itime, const float* __restrict__ it_t,
    const float* __restrict__ Wl, const float* __restrict__ blv,
    const float* __restrict__ Wg, const float* __restrict__ bgv,
    const float* __restrict__ Wf, const float* __restrict__ bfv,
    const float* __restrict__ le_ws,
    float* __restrict__ PRE_l, float* __restrict__ PRE_g, float* __restrict__ PRE_f)
{
    __shared__ float xS[NPAIR * 384];   // [pair][0:128 lp |128:256 it |256:384 lc]
    __shared__ int ivS[NPAIR], t0S[NPAIR];
    const int tid = threadIdx.x;
    const int p0 = blockIdx.x * NPAIR;
    if (tid < NPAIR) {
        int p = p0 + tid;
        int b = p / T_SZ, t = p - b * T_SZ;
        ivS[tid] = itime[b * S_SZ + t + 1];
        t0S[tid] = (t == 0);
    }
    __syncthreads();
    #pragma unroll
    for (int it = 0; it < 6; ++it) {
        int f = it * 256 + tid;            // 1536 f32x4 chunks
        int pr = f / 96, c = f - pr * 96;
        int p = p0 + pr;
        f32x4 v;
        if (c < 32) {
            v = t0S[pr] ? (f32x4){0.f, 0.f, 0.f, 0.f}
                        : *(const f32x4*)(le_ws + (p - 1) * DK + 4 * c);
        } else if (c < 64) {
            v = *(const f32x4*)(it_t + ivS[pr] * DK + 4 * (c - 32));
        } else {
            v = *(const f32x4*)(le_ws + p * DK + 4 * (c - 64));
        }
        *(f32x4*)(xS + pr * 384 + 4 * c) = v;
    }
    __syncthreads();
    const int o = tid & 127, g = tid >> 7;
    const float* wl = Wl + o * 512;
    const float* wg = Wg + o * 512;
    const float bl0 = blv[o], bg0 = bgv[o];
    float al[8], ag[8];
    #pragma unroll
    for (int i = 0; i < 8; ++i) { al[i] = bl0; ag[i] = bg0; }
    #pragma unroll 2
    for (int k4 = 0; k4 < 96; ++k4) {
        f32x4 w  = *(const f32x4*)(wl + 4 * k4);
        f32x4 w2 = *(const f32x4*)(wg + 4 * k4);
        #pragma unroll
        for (int i = 0; i < 8; ++i) {
            f32x4 x = *(const f32x4*)(xS + (g * 8 + i) * 384 + 4 * k4);
            al[i] += w[0] * x[0] + w[1] * x[1] + w[2] * x[2] + w[3] * x[3];
            ag[i] += w2[0] * x[0] + w2[1] * x[1] + w2[2] * x[2] + w2[3] * x[3];
        }
    }
    const float bf0 = bfv[o];
    float af[8];
    #pragma unroll
    for (int i = 0; i < 8; ++i) af[i] = bf0;
    const float* wf = Wf + o * 384 + 256;
    #pragma unroll 2
    for (int k4 = 0; k4 < 32; ++k4) {
        f32x4 w = *(const f32x4*)(wf + 4 * k4);
        #pragma unroll
        for (int i = 0; i < 8; ++i) {
            f32x4 x = *(const f32x4*)(xS + (g * 8 + i) * 384 + 128 + 4 * k4);
            af[i] += w[0] * x[0] + w[1] * x[1] + w[2] * x[2] + w[3] * x[3];
        }
    }
    #pragma unroll
    for (int i = 0; i < 8; ++i) {
        size_t idx = (size_t)(p0 + g * 8 + i) * DK + o;
        PRE_l[idx] = al[i];
        PRE_g[idx] = ag[i];
        PRE_f[idx] = af[i];
    }
}

// ---------------------------------------------------------------------------
// Kernel C: sequential scan, 2-way skill-split (UNCHANGED from R1 — control)
// ---------------------------------------------------------------------------
__global__ __launch_bounds__(512, 1) void k_main(
    const int* __restrict__ eid, const float* __restrict__ qmat,
    const float* __restrict__ Wl, const float* __restrict__ Wg,
    const float* __restrict__ Wf, const float* __restrict__ h0,
    const float* __restrict__ PRE_l, const float* __restrict__ PRE_g,
    const float* __restrict__ PRE_f, float* __restrict__ ht_ws,
    float* __restrict__ xbuf, int* __restrict__ flags)
{
    extern __shared__ char smem[];
    u16*   hS   = (u16*)smem;                    // 128*136*2 = 34816
    float* part = (float*)(smem + 34816);        // 128*68*4  = 34816 -> 69632
    u16*   htbf = (u16*)(smem + 69632);          // hi[128], lo[128] -> 70144
    u16*   LGb  = (u16*)(smem + 70144);          // hi[128], lo[128] -> 70656
    float* LGf  = (float*)(smem + 70656);        // 512 -> 71168
    float* cS   = (float*)(smem + 71168);        // 512 -> 71680

    const int b    = blockIdx.x;
    const int sh   = blockIdx.y;     // which skill half this block owns
    const int po   = 1 - sh;         // partner
    const int tid  = threadIdx.x;
    const int w    = tid >> 6;
    const int lane = tid & 63;
    const int quad = lane >> 4;
    const int l4   = lane & 15;
    const int ih   = w & 1;          // d-half
    const int jh   = w >> 1;         // 32-skill quarter within this block's half

    float* xb  = xbuf  + b * 512;    // [sh][slot][128] f32
    int*   flg = flags + b * 16;     // [sh][wave] monotonic step counters

    // ---- persistent A-frags ----
    u16x8 afr[4][4];
    #pragma unroll
    for (int mt = 0; mt < 4; ++mt)
        #pragma unroll
        for (int kt = 0; kt < 4; ++kt) {
            const float* p = Wf + (64 * ih + 16 * mt + l4) * 384 + 32 * kt + quad * 8;
            afr[mt][kt] = cvt8(*(const f32x4*)p, *(const f32x4*)(p + 4));
        }
    u16x8 azf[2][4];
    #pragma unroll
    for (int mt = 0; mt < 2; ++mt)
        #pragma unroll
        for (int kt = 0; kt < 4; ++kt) {
            int d = 16 * w + 8 * mt + (l4 >> 1);
            const float* base = (l4 & 1) ? Wg : Wl;
            const float* p = base + d * 512 + 384 + 32 * kt + quad * 8;
            azf[mt][kt] = cvt8(*(const f32x4*)p, *(const f32x4*)(p + 4));
        }
    u16x8 acf[4];
    #pragma unroll
    for (int kt = 0; kt < 4; ++kt) {
        const float* p = Wf + (16 * w + l4) * 384 + 128 + 32 * kt + quad * 8;
        acf[kt] = cvt8(*(const f32x4*)p, *(const f32x4*)(p + 4));
    }

    // ---- h0 (own half only) -> fp32 regs + bf16 LDS mirror ----
    f32x4 hreg[4][2];
    #pragma unroll
    for (int mt = 0; mt < 4; ++mt) {
        int d0 = 64 * ih + 16 * mt + quad * 4;
        #pragma unroll
        for (int nt = 0; nt < 2; ++nt) {
            int s = 32 * jh + 16 * nt + l4;
            f32x4 hv = *(const f32x4*)(h0 + (SHALF * sh + s) * DK + d0);
            hreg[mt][nt] = hv;
            *(u16x4*)(hS + s * RL + d0) = cvt4(hv);
        }
    }

    float kvt[2];
    {
        int e0 = eid[b * S_SZ];
        #pragma unroll
        for (int nt = 0; nt < 2; ++nt)
            kvt[nt] = qmat[e0 * SKILL + SHALF * sh + 32 * jh + 16 * nt + l4];
    }

    f32x4 accF[4][2];

    // ---- prologue: partial h~0, exchange, Zf(t=0) ----
    {
        float htp[16];
        #pragma unroll
        for (int v2 = 0; v2 < 16; ++v2) htp[v2] = 0.f;
        #pragma unroll
        for (int nt = 0; nt < 2; ++nt)
            #pragma unroll
            for (int mt = 0; mt < 4; ++mt)
                #pragma unroll
                for (int r = 0; r < 4; ++r)
                    htp[mt * 4 + r] += kvt[nt] * hreg[mt][nt][r];
        #pragma unroll
        for (int mt = 0; mt < 4; ++mt)
            #pragma unroll
            for (int r = 0; r < 4; ++r)
                part[(64 * ih + 16 * mt + quad * 4 + r) * PP + jh * 16 + l4] = htp[mt * 4 + r];
        __syncthreads();
        int d = tid >> 2, kq = tid & 3;
        const float* pp = part + d * PP + kq * 16;
        float v = 0.f;
        #pragma unroll
        for (int i4 = 0; i4 < 4; ++i4) {
            f32x4 x = *(const f32x4*)(pp + 4 * i4);
            v += x[0] + x[1] + x[2] + x[3];
        }
        v += __shfl_xor(v, 1, 64);
        v += __shfl_xor(v, 2, 64);
        if (kq == 0)
            __hip_atomic_store(xb + (sh * 2 + 1) * 128 + d, v,
                               __ATOMIC_RELAXED, __HIP_MEMORY_SCOPE_AGENT);
        asm volatile("s_waitcnt vmcnt(0)" ::: "memory");
        if (lane == 0)
            __hip_atomic_store(flg + sh * 8 + w, 1,
                               __ATOMIC_RELAXED, __HIP_MEMORY_SCOPE_AGENT);
        #pragma unroll
        for (int mt = 0; mt < 4; ++mt)
            #pragma unroll
            for (int n2 = 0; n2 < 2; ++n2)
                accF[mt][n2] = (f32x4){0.f, 0.f, 0.f, 0.f};
        #pragma unroll
        for (int n2 = 0; n2 < 2; ++n2) {
            const u16* bp = hS + (32 * jh + 16 * n2 + l4) * RL + quad * 8;
            u16x8 bfr[4];
            #pragma unroll
            for (int kt = 0; kt < 4; ++kt) bfr[kt] = *(const u16x8*)(bp + kt * 32);
            #pragma unroll
            for (int mt = 0; mt < 4; ++mt)
                #pragma unroll
                for (int kt = 0; kt < 4; ++kt)
                    accF[mt][n2] = mfma16(afr[mt][kt], bfr[kt], accF[mt][n2]);
        }
        if (lane == 0) {
            int spins = 0;
            while (__hip_atomic_load(flg + po * 8 + w,
                                     __ATOMIC_RELAXED, __HIP_MEMORY_SCOPE_AGENT) < 1) {
                __builtin_amdgcn_s_sleep(1);
                if (++spins > (1 << 20)) break;
            }
        }
        asm volatile("" ::: "memory");
        if (kq == 0) {
            float o = __hip_atomic_load(xb + (po * 2 + 1) * 128 + d,
                                        __ATOMIC_RELAXED, __HIP_MEMORY_SCOPE_AGENT);
            v += o;
            float hf = (float)(__bf16)v;
            htbf[d] = bfu(v);
            htbf[128 + d] = bfu(v - hf);
        }
        __syncthreads();
    }

    for (int t = 0; t < T_SZ; ++t) {
        const size_t tb = (size_t)(b * T_SZ + t) * DK;
        int en = eid[b * S_SZ + t + 1];
        float kvn[2];
        #pragma unroll
        for (int nt = 0; nt < 2; ++nt)
            kvn[nt] = qmat[en * SKILL + SHALF * sh + 32 * jh + 16 * nt + l4];
        f32x2 pl[2], pg[2];
        #pragma unroll
        for (int mt = 0; mt < 2; ++mt) {
            int d0 = 16 * w + 8 * mt + 2 * quad;
            pl[mt] = *(const f32x2*)(PRE_l + tb + d0);
            pg[mt] = *(const f32x2*)(PRE_g + tb + d0);
        }
        f32x4 pf = *(const f32x4*)(PRE_f + tb + 16 * w + quad * 4);

        f32x4 accZ[2];
        accZ[0] = (f32x4){0.f, 0.f, 0.f, 0.f};
        accZ[1] = (f32x4){0.f, 0.f, 0.f, 0.f};
        #pragma unroll
        for (int kt = 0; kt < 4; ++kt) {
            u16x8 bh = *(const u16x8*)(htbf + 32 * kt + quad * 8);
            u16x8 bl = *(const u16x8*)(htbf + 128 + 32 * kt + quad * 8);
            #pragma unroll
            for (int mt = 0; mt < 2; ++mt) {
                accZ[mt] = mfma16(azf[mt][kt], bh, accZ[mt]);
                accZ[mt] = mfma16(azf[mt][kt], bl, accZ[mt]);
            }
        }
        #pragma unroll
        for (int mt = 0; mt < 2; ++mt) {
            u32 hpack = 0, lpack = 0;
            f32x2 fpack;
            #pragma unroll
            for (int rp = 0; rp < 2; ++rp) {
                float zl = accZ[mt][2 * rp] + pl[mt][rp];
                float zg = accZ[mt][2 * rp + 1] + pg[mt][rp];
                float LGv = sigm(zg) * (tanh_f(zl) + 1.f) * 0.5f;
                float hif = (float)(__bf16)LGv;
                hpack |= ((u32)bfu(LGv)) << (16 * rp);
                lpack |= ((u32)bfu(LGv - hif)) << (16 * rp);
                fpack[rp] = LGv;
            }
            if (l4 == 0) {
                int d0 = 16 * w + 8 * mt + 2 * quad;
                *(u32*)(LGb + d0) = hpack;
                *(u32*)(LGb + 128 + d0) = lpack;
                *(f32x2*)(LGf + d0) = fpack;
            }
        }
        __syncthreads();   // B: LG ready

        {
            f32x4 accC = (f32x4){0.f, 0.f, 0.f, 0.f};
            #pragma unroll
            for (int kt = 0; kt < 4; ++kt) {
                u16x8 bh = *(const u16x8*)(LGb + 32 * kt + quad * 8);
                u16x8 bl = *(const u16x8*)(LGb + 128 + 32 * kt + quad * 8);
                accC = mfma16(acf[kt], bh, accC);
                accC = mfma16(acf[kt], bl, accC);
            }
            accC += pf;
            if (l4 == 0) *(f32x4*)(cS + 16 * w + quad * 4) = accC;
        }
        __syncthreads();   // C: c ready

        float htp[16];
        #pragma unroll
        for (int v2 = 0; v2 < 16; ++v2) htp[v2] = 0.f;
        #pragma unroll
        for (int mt = 0; mt < 4; ++mt) {
            int d0 = 64 * ih + 16 * mt + quad * 4;
            f32x4 lg = *(const f32x4*)(LGf + d0);
            f32x4 cc = *(const f32x4*)(cS + d0);
            #pragma unroll
            for (int n2 = 0; n2 < 2; ++n2) {
                int s = 32 * jh + 16 * n2 + l4;
                f32x4 hv;
                #pragma unroll
                for (int r = 0; r < 4; ++r) {
                    float f = sigm(accF[mt][n2][r] + cc[r]);
                    float hn = kvt[n2] * lg[r] + f * hreg[mt][n2][r];
                    hreg[mt][n2][r] = hn;
                    htp[mt * 4 + r] += kvn[n2] * hn;
                    hv[r] = hn;
                }
                *(u16x4*)(hS + s * RL + d0) = cvt4(hv);
            }
        }
        #pragma unroll
        for (int mt = 0; mt < 4; ++mt)
            #pragma unroll
            for (int r = 0; r < 4; ++r)
                part[(64 * ih + 16 * mt + quad * 4 + r) * PP + jh * 16 + l4] = htp[mt * 4 + r];
        kvt[0] = kvn[0];
        kvt[1] = kvn[1];
        __syncthreads();   // E: partials + hS(t+1) ready

        {
            int d = tid >> 2, kq = tid & 3;
            const float* pp = part + d * PP + kq * 16;
            float v = 0.f;
            #pragma unroll
            for (int i4 = 0; i4 < 4; ++i4) {
                f32x4 x = *(const f32x4*)(pp + 4 * i4);
                v += x[0] + x[1] + x[2] + x[3];
            }
            v += __shfl_xor(v, 1, 64);
            v += __shfl_xor(v, 2, 64);
            int slot = t & 1;
            if (kq == 0)
                __hip_atomic_store(xb + (sh * 2 + slot) * 128 + d, v,
                                   __ATOMIC_RELAXED, __HIP_MEMORY_SCOPE_AGENT);
            asm volatile("s_waitcnt vmcnt(0)" ::: "memory");
            if (lane == 0)
                __hip_atomic_store(flg + sh * 8 + w, t + 2,
                                   __ATOMIC_RELAXED, __HIP_MEMORY_SCOPE_AGENT);
            #pragma unroll
            for (int mt = 0; mt < 4; ++mt)
                #pragma unroll
                for (int n2 = 0; n2 < 2; ++n2)
                    accF[mt][n2] = (f32x4){0.f, 0.f, 0.f, 0.f};
            #pragma unroll
            for (int n2 = 0; n2 < 2; ++n2) {
                const u16* bp = hS + (32 * jh + 16 * n2 + l4) * RL + quad * 8;
                u16x8 bfr[4];
                #pragma unroll
                for (int kt = 0; kt < 4; ++kt) bfr[kt] = *(const u16x8*)(bp + kt * 32);
                #pragma unroll
                for (int mt = 0; mt < 4; ++mt)
                    #pragma unroll
                    for (int kt = 0; kt < 4; ++kt)
                        accF[mt][n2] = mfma16(afr[mt][kt], bfr[kt], accF[mt][n2]);
            }
            if (lane == 0) {
                int spins = 0;
                while (__hip_atomic_load(flg + po * 8 + w,
                                         __ATOMIC_RELAXED, __HIP_MEMORY_SCOPE_AGENT) < t + 2) {
                    __builtin_amdgcn_s_sleep(1);
                    if (++spins > (1 << 20)) break;
                }
            }
            asm volatile("" ::: "memory");
            if (kq == 0) {
                float o = __hip_atomic_load(xb + (po * 2 + slot) * 128 + d,
                                            __ATOMIC_RELAXED, __HIP_MEMORY_SCOPE_AGENT);
                v += o;
                float hf = (float)(__bf16)v;
                htbf[d] = bfu(v);
                htbf[128 + d] = bfu(v - hf);
                if (sh == 0) ht_ws[tb + d] = v;
            }
        }
        __syncthreads();   // TOP: h~ ready
    }
}

// ---------------------------------------------------------------------------
// Kernel D (v2): pred, same weight-hoisted restructure. 254 blocks x 16 pairs.
// ---------------------------------------------------------------------------
__global__ __launch_bounds__(256) void k_pred(
    const int* __restrict__ eid, const float* __restrict__ ex_t,
    const float* __restrict__ Wp, const float* __restrict__ bpv,
    const float* __restrict__ ht_ws, float* __restrict__ out)
{
    __shared__ float xS[NPAIR * 256];   // [pair][0:128 ex(t+1) | 128:256 ht]
    __shared__ int eS[NPAIR];
    const int tid = threadIdx.x;
    const int p0 = blockIdx.x * NPAIR;
    if (tid < NPAIR) {
        int p = p0 + tid;
        int b = p / T_SZ, t = p - b * T_SZ;
        eS[tid] = eid[b * S_SZ + t + 1];
    }
    __syncthreads();
    #pragma unroll
    for (int it = 0; it < 4; ++it) {
        int f = it * 256 + tid;
        int pr = f >> 6, c = f & 63;
        const float* src = (c < 32) ? ex_t + eS[pr] * DK + 4 * c
                                    : ht_ws + (size_t)(p0 + pr) * DK + 4 * (c - 32);
        *(f32x4*)(xS + pr * 256 + 4 * c) = *(const f32x4*)src;
    }
    __syncthreads();
    const int o = tid & 127, g = tid >> 7;
    const float* wr = Wp + o * 256;
    const float bias = bpv[o];
    float acc[8];
    #pragma unroll
    for (int i = 0; i < 8; ++i) acc[i] = bias;
    #pragma unroll 2
    for (int k4 = 0; k4 < 64; ++k4) {
        f32x4 w = *(const f32x4*)(wr + 4 * k4);
        #pragma unroll
        for (int i = 0; i < 8; ++i) {
            f32x4 x = *(const f32x4*)(xS + (g * 8 + i) * 256 + 4 * k4);
            acc[i] += w[0] * x[0] + w[1] * x[1] + w[2] * x[2] + w[3] * x[3];
        }
    }
    #pragma unroll
    for (int i = 0; i < 8; ++i)
        out[(size_t)(p0 + g * 8 + i) * DK + o] = sigm(acc[i]);
}

extern "C" void kernel_launch(void* const* d_in, const int* in_sizes, int n_in,
                              void* d_out, int out_size, void* d_ws, size_t ws_size,
                              hipStream_t stream) {
    const int* eid     = (const int*)d_in[0];
    const int* atime   = (const int*)d_in[1];
    const int* itime   = (const int*)d_in[2];
    const int* ansv    = (const int*)d_in[3];
    const float* qmat  = (const float*)d_in[4];
    const float* ex_t  = (const float*)d_in[5];
    const float* at_t  = (const float*)d_in[6];
    const float* it_t  = (const float*)d_in[7];
    const float* W1    = (const float*)d_in[8];
    const float* b1    = (const float*)d_in[9];
    const float* Wl    = (const float*)d_in[10];
    const float* blv   = (const float*)d_in[11];
    const float* Wg    = (const float*)d_in[12];
    const float* bgv   = (const float*)d_in[13];
    const float* Wf    = (const float*)d_in[14];
    const float* bfv   = (const float*)d_in[15];
    const float* Wp    = (const float*)d_in[16];
    const float* bpv   = (const float*)d_in[17];
    const float* h0    = (const float*)d_in[18];
    float* out = (float*)d_out;

    const size_t SZ = (size_t)B_SZ * T_SZ * DK;
    float* wsf   = (float*)d_ws;
    float* le_ws = wsf;
    float* PRE_l = wsf + SZ;
    float* PRE_g = wsf + 2 * SZ;
    float* PRE_f = wsf + 3 * SZ;
    float* ht_ws = wsf + 4 * SZ;
    // le_ws is dead after k_pre -> reuse its head for the exchange buffers.
    float* xbuf  = le_ws;                      // 32*2*2*128 f32 = 64 KiB
    int*   flags = (int*)(le_ws + 16384);      // 32*16 ints = 2 KiB

    hipFuncSetAttribute((const void*)k_main,
                        hipFuncAttributeMaxDynamicSharedMemorySize, 86016);

    dim3 gaux(254);
    k_le  <<<gaux, 256, 0, stream>>>(eid, atime, ansv, ex_t, at_t, W1, b1, le_ws);
    k_pre <<<gaux, 256, 0, stream>>>(itime, it_t, Wl, blv, Wg, bgv, Wf, bfv,
                                     le_ws, PRE_l, PRE_g, PRE_f);
    hipMemsetAsync(flags, 0, 32 * 16 * sizeof(int), stream);
    k_main<<<dim3(B_SZ, 2), 512, 86016, stream>>>(eid, qmat, Wl, Wg, Wf, h0,
                                                  PRE_l, PRE_g, PRE_f, ht_ws,
                                                  xbuf, flags);
    k_pred<<<gaux, 256, 0, stream>>>(eid, ex_t, Wp, bpv, ht_ws, out);
}

// Round 3
// 693.086 us; speedup vs baseline: 1.9220x; 1.1129x over previous
//
#include <hip/hip_runtime.h>

typedef unsigned int u32;
typedef unsigned short u16;
typedef u16 u16x8 __attribute__((ext_vector_type(8)));
typedef u16 u16x4 __attribute__((ext_vector_type(4)));
typedef __bf16 bf16x8 __attribute__((ext_vector_type(8)));
typedef __bf16 bf16x4v __attribute__((ext_vector_type(4)));
typedef float f32x4 __attribute__((ext_vector_type(4)));
typedef float f32x2 __attribute__((ext_vector_type(2)));

#define B_SZ 32
#define S_SZ 128
#define T_SZ 127
#define DK 128
#define SKILL 256
#define SQTR 64    /* skills per block after 4-way split */
#define RL 136     /* hS row pitch (u16): 128 + 8 pad */
#define PP 68      /* part row pitch (f32): 64 + 4 pad */
#define NPAIR 8    /* (b,t) pairs per aux block; 4064 = 508*8 */

__device__ __forceinline__ u16x4 cvt4(f32x4 v) {
    return __builtin_bit_cast(u16x4, __builtin_convertvector(v, bf16x4v));
}
__device__ __forceinline__ u16x8 cvt8(f32x4 a, f32x4 b) {
    u16x4 x = cvt4(a), y = cvt4(b);
    u16x8 r;
    r[0]=x[0]; r[1]=x[1]; r[2]=x[2]; r[3]=x[3];
    r[4]=y[0]; r[5]=y[1]; r[6]=y[2]; r[7]=y[3];
    return r;
}
__device__ __forceinline__ u16 bfu(float x) {
    return __builtin_bit_cast(u16, (__bf16)x);
}
__device__ __forceinline__ float sigm(float x) {
    float e = __builtin_amdgcn_exp2f(-1.44269504f * x);
    return __builtin_amdgcn_rcpf(1.f + e);
}
__device__ __forceinline__ float tanh_f(float x) {
    float e = __builtin_amdgcn_exp2f(-2.88539008f * x);
    return 2.f * __builtin_amdgcn_rcpf(1.f + e) - 1.f;
}
__device__ __forceinline__ f32x4 mfma16(u16x8 a, u16x8 bb, f32x4 c) {
    return __builtin_amdgcn_mfma_f32_16x16x32_bf16(
        __builtin_bit_cast(bf16x8, a), __builtin_bit_cast(bf16x8, bb), c, 0, 0, 0);
}

// ---------------------------------------------------------------------------
// Kernel A: le = W1 @ [ex | at | ans] + b1. Weight-hoisted, NPAIR=8.
// ---------------------------------------------------------------------------
__global__ __launch_bounds__(256) void k_le(
    const int* __restrict__ eid, const int* __restrict__ atime,
    const int* __restrict__ ansv, const float* __restrict__ ex_t,
    const float* __restrict__ at_t, const float* __restrict__ W1,
    const float* __restrict__ b1, float* __restrict__ le_ws)
{
    __shared__ float xS[NPAIR * 256];   // [pair][0:128 ex | 128:256 at]
    __shared__ int   eS[NPAIR], aS[NPAIR];
    __shared__ float avS[NPAIR];
    const int tid = threadIdx.x;
    const int p0 = blockIdx.x * NPAIR;
    if (tid < NPAIR) {
        int p = p0 + tid;
        int b = p / T_SZ, t = p - b * T_SZ;
        eS[tid] = eid[b * S_SZ + t];
        aS[tid] = atime[b * S_SZ + t];
        avS[tid] = (float)ansv[b * S_SZ + t];
    }
    __syncthreads();
    #pragma unroll
    for (int it = 0; it < 2; ++it) {
        int f = it * 256 + tid;            // 512 f32x4 chunks
        int pr = f >> 6, c = f & 63;
        const float* src = (c < 32) ? ex_t + eS[pr] * DK + 4 * c
                                    : at_t + aS[pr] * DK + 4 * (c - 32);
        *(f32x4*)(xS + pr * 256 + 4 * c) = *(const f32x4*)src;
    }
    __syncthreads();
    const int o = tid & 127, g = tid >> 7;
    const float* wr = W1 + o * 384;
    const float bias = b1[o];
    float acc[4];
    #pragma unroll
    for (int i = 0; i < 4; ++i) acc[i] = bias;
    #pragma unroll 2
    for (int k4 = 0; k4 < 64; ++k4) {
        f32x4 w = *(const f32x4*)(wr + 4 * k4);
        #pragma unroll
        for (int i = 0; i < 4; ++i) {
            f32x4 x = *(const f32x4*)(xS + (g * 4 + i) * 256 + 4 * k4);
            acc[i] += w[0] * x[0] + w[1] * x[1] + w[2] * x[2] + w[3] * x[3];
        }
    }
    float wsum = 0.f;
    #pragma unroll 4
    for (int k4 = 64; k4 < 96; ++k4) {
        f32x4 w = *(const f32x4*)(wr + 4 * k4);
        wsum += w[0] + w[1] + w[2] + w[3];
    }
    #pragma unroll
    for (int i = 0; i < 4; ++i) {
        int p = p0 + g * 4 + i;
        le_ws[p * DK + o] = acc[i] + avS[g * 4 + i] * wsum;
    }
}

// ---------------------------------------------------------------------------
// Kernel B: gate pre-activations. Weight-hoisted, NPAIR=8.
// ---------------------------------------------------------------------------
__global__ __launch_bounds__(256) void k_pre(
    const int* __restrict__ itime, const float* __restrict__ it_t,
    const float* __restrict__ Wl, const float* __restrict__ blv,
    const float* __restrict__ Wg, const float* __restrict__ bgv,
    const float* __restrict__ Wf, const float* __restrict__ bfv,
    const float* __restrict__ le_ws,
    float* __restrict__ PRE_l, float* __restrict__ PRE_g, float* __restrict__ PRE_f)
{
    __shared__ float xS[NPAIR * 384];   // [pair][0:128 lp |128:256 it |256:384 lc]
    __shared__ int ivS[NPAIR], t0S[NPAIR];
    const int tid = threadIdx.x;
    const int p0 = blockIdx.x * NPAIR;
    if (tid < NPAIR) {
        int p = p0 + tid;
        int b = p / T_SZ, t = p - b * T_SZ;
        ivS[tid] = itime[b * S_SZ + t + 1];
        t0S[tid] = (t == 0);
    }
    __syncthreads();
    #pragma unroll
    for (int it = 0; it < 3; ++it) {
        int f = it * 256 + tid;            // 768 f32x4 chunks
        int pr = f / 96, c = f - pr * 96;
        int p = p0 + pr;
        f32x4 v;
        if (c < 32) {
            v = t0S[pr] ? (f32x4){0.f, 0.f, 0.f, 0.f}
                        : *(const f32x4*)(le_ws + (p - 1) * DK + 4 * c);
        } else if (c < 64) {
            v = *(const f32x4*)(it_t + ivS[pr] * DK + 4 * (c - 32));
        } else {
            v = *(const f32x4*)(le_ws + p * DK + 4 * (c - 64));
        }
        *(f32x4*)(xS + pr * 384 + 4 * c) = v;
    }
    __syncthreads();
    const int o = tid & 127, g = tid >> 7;
    const float* wl = Wl + o * 512;
    const float* wg = Wg + o * 512;
    const float bl0 = blv[o], bg0 = bgv[o];
    float al[4], ag[4];
    #pragma unroll
    for (int i = 0; i < 4; ++i) { al[i] = bl0; ag[i] = bg0; }
    #pragma unroll 2
    for (int k4 = 0; k4 < 96; ++k4) {
        f32x4 w  = *(const f32x4*)(wl + 4 * k4);
        f32x4 w2 = *(const f32x4*)(wg + 4 * k4);
        #pragma unroll
        for (int i = 0; i < 4; ++i) {
            f32x4 x = *(const f32x4*)(xS + (g * 4 + i) * 384 + 4 * k4);
            al[i] += w[0] * x[0] + w[1] * x[1] + w[2] * x[2] + w[3] * x[3];
            ag[i] += w2[0] * x[0] + w2[1] * x[1] + w2[2] * x[2] + w2[3] * x[3];
        }
    }
    const float bf0 = bfv[o];
    float af[4];
    #pragma unroll
    for (int i = 0; i < 4; ++i) af[i] = bf0;
    const float* wf = Wf + o * 384 + 256;
    #pragma unroll 2
    for (int k4 = 0; k4 < 32; ++k4) {
        f32x4 w = *(const f32x4*)(wf + 4 * k4);
        #pragma unroll
        for (int i = 0; i < 4; ++i) {
            f32x4 x = *(const f32x4*)(xS + (g * 4 + i) * 384 + 128 + 4 * k4);
            af[i] += w[0] * x[0] + w[1] * x[1] + w[2] * x[2] + w[3] * x[3];
        }
    }
    #pragma unroll
    for (int i = 0; i < 4; ++i) {
        size_t idx = (size_t)(p0 + g * 4 + i) * DK + o;
        PRE_l[idx] = al[i];
        PRE_g[idx] = ag[i];
        PRE_f[idx] = af[i];
    }
}

// ---------------------------------------------------------------------------
// Kernel C: sequential scan, 4-way skill-split: grid (B,4), block (b,qid)
// owns skills 64*qid..64*qid+63. Per-step 4-way all-gather of 128-float
// quarter-partials via L3 (relaxed agent-scope atomics + per-wave monotonic
// flags; data store -> vmcnt(0) -> flag). h~ summed in canonical q0..q3
// order so all 4 blocks compute bit-identical h~. z/LG/c redundant per
// block; Zf(t+1) computed in the publish->spin gap (hS stable there).
// ---------------------------------------------------------------------------
__global__ __launch_bounds__(512, 1) void k_main(
    const int* __restrict__ eid, const float* __restrict__ qmat,
    const float* __restrict__ Wl, const float* __restrict__ Wg,
    const float* __restrict__ Wf, const float* __restrict__ h0,
    const float* __restrict__ PRE_l, const float* __restrict__ PRE_g,
    const float* __restrict__ PRE_f, float* __restrict__ ht_ws,
    float* __restrict__ xbuf, int* __restrict__ flags)
{
    extern __shared__ char smem[];
    u16*   hS   = (u16*)smem;                    // 64*136*2  = 17408
    float* part = (float*)(smem + 17408);        // 128*68*4  = 34816 -> 52224
    u16*   htbf = (u16*)(smem + 52224);          // hi[128], lo[128] -> 52736
    u16*   LGb  = (u16*)(smem + 52736);          // hi[128], lo[128] -> 53248
    float* LGf  = (float*)(smem + 53248);        // 512 -> 53760
    float* cS   = (float*)(smem + 53760);        // 512 -> 54272

    const int b    = blockIdx.x;
    const int qid  = blockIdx.y;     // skill quarter this block owns
    const int tid  = threadIdx.x;
    const int w    = tid >> 6;
    const int lane = tid & 63;
    const int quad = lane >> 4;
    const int l4   = lane & 15;
    const int ih   = w & 1;          // d-half
    const int jh   = w >> 1;         // 16-skill group within this quarter

    float* xb  = xbuf  + b * 1024;   // [qid][slot][128] f32
    int*   flg = flags + b * 32;     // [qid][wave] monotonic step counters

    // partner flag index for the spin: lanes 0..2 watch the 3 other quarters
    const int pq = (lane < 3) ? ((lane < qid) ? lane : lane + 1) : qid;

    // ---- persistent A-frags ----
    u16x8 afr[4][4];
    #pragma unroll
    for (int mt = 0; mt < 4; ++mt)
        #pragma unroll
        for (int kt = 0; kt < 4; ++kt) {
            const float* p = Wf + (64 * ih + 16 * mt + l4) * 384 + 32 * kt + quad * 8;
            afr[mt][kt] = cvt8(*(const f32x4*)p, *(const f32x4*)(p + 4));
        }
    u16x8 azf[2][4];
    #pragma unroll
    for (int mt = 0; mt < 2; ++mt)
        #pragma unroll
        for (int kt = 0; kt < 4; ++kt) {
            int d = 16 * w + 8 * mt + (l4 >> 1);
            const float* base = (l4 & 1) ? Wg : Wl;
            const float* p = base + d * 512 + 384 + 32 * kt + quad * 8;
            azf[mt][kt] = cvt8(*(const f32x4*)p, *(const f32x4*)(p + 4));
        }
    u16x8 acf[4];
    #pragma unroll
    for (int kt = 0; kt < 4; ++kt) {
        const float* p = Wf + (16 * w + l4) * 384 + 128 + 32 * kt + quad * 8;
        acf[kt] = cvt8(*(const f32x4*)p, *(const f32x4*)(p + 4));
    }

    // ---- h0 (own quarter) -> fp32 regs + bf16 LDS mirror ----
    const int sl = 16 * jh + l4;     // local skill row 0..63
    f32x4 hreg[4];
    #pragma unroll
    for (int mt = 0; mt < 4; ++mt) {
        int d0 = 64 * ih + 16 * mt + quad * 4;
        f32x4 hv = *(const f32x4*)(h0 + (SQTR * qid + sl) * DK + d0);
        hreg[mt] = hv;
        *(u16x4*)(hS + sl * RL + d0) = cvt4(hv);
    }

    float kvt = qmat[eid[b * S_SZ] * SKILL + SQTR * qid + sl];

    f32x4 accF[4];

    // ---- prologue: partial h~0, exchange, Zf(t=0) ----
    {
        float htp[16];
        #pragma unroll
        for (int mt = 0; mt < 4; ++mt)
            #pragma unroll
            for (int r = 0; r < 4; ++r)
                htp[mt * 4 + r] = kvt * hreg[mt][r];
        #pragma unroll
        for (int mt = 0; mt < 4; ++mt)
            #pragma unroll
            for (int r = 0; r < 4; ++r)
                part[(64 * ih + 16 * mt + quad * 4 + r) * PP + jh * 16 + l4] = htp[mt * 4 + r];
        __syncthreads();
        int d = tid >> 2, kq = tid & 3;
        const float* pp = part + d * PP + kq * 16;
        float v = 0.f;
        #pragma unroll
        for (int i4 = 0; i4 < 4; ++i4) {
            f32x4 x = *(const f32x4*)(pp + 4 * i4);
            v += x[0] + x[1] + x[2] + x[3];
        }
        v += __shfl_xor(v, 1, 64);
        v += __shfl_xor(v, 2, 64);
        if (kq == 0)
            __hip_atomic_store(xb + (qid * 2 + 1) * 128 + d, v,
                               __ATOMIC_RELAXED, __HIP_MEMORY_SCOPE_AGENT);
        asm volatile("s_waitcnt vmcnt(0)" ::: "memory");
        if (lane == 0)
            __hip_atomic_store(flg + qid * 8 + w, 1,
                               __ATOMIC_RELAXED, __HIP_MEMORY_SCOPE_AGENT);
        // Zf for t=0 overlaps partners' publish
        #pragma unroll
        for (int mt = 0; mt < 4; ++mt)
            accF[mt] = (f32x4){0.f, 0.f, 0.f, 0.f};
        {
            const u16* bp = hS + sl * RL + quad * 8;
            u16x8 bfr[4];
            #pragma unroll
            for (int kt = 0; kt < 4; ++kt) bfr[kt] = *(const u16x8*)(bp + kt * 32);
            #pragma unroll
            for (int mt = 0; mt < 4; ++mt)
                #pragma unroll
                for (int kt = 0; kt < 4; ++kt)
                    accF[mt] = mfma16(afr[mt][kt], bfr[kt], accF[mt]);
        }
        {
            int spins = 0;
            while (true) {
                int fv = __hip_atomic_load(flg + pq * 8 + w,
                                           __ATOMIC_RELAXED, __HIP_MEMORY_SCOPE_AGENT);
                if (__all(fv >= 1)) break;
                __builtin_amdgcn_s_sleep(1);
                if (++spins > (1 << 20)) break;
            }
        }
        asm volatile("" ::: "memory");
        if (kq == 0) {
            float q0 = (qid == 0) ? v : __hip_atomic_load(xb + (0 * 2 + 1) * 128 + d, __ATOMIC_RELAXED, __HIP_MEMORY_SCOPE_AGENT);
            float q1 = (qid == 1) ? v : __hip_atomic_load(xb + (1 * 2 + 1) * 128 + d, __ATOMIC_RELAXED, __HIP_MEMORY_SCOPE_AGENT);
            float q2 = (qid == 2) ? v : __hip_atomic_load(xb + (2 * 2 + 1) * 128 + d, __ATOMIC_RELAXED, __HIP_MEMORY_SCOPE_AGENT);
            float q3 = (qid == 3) ? v : __hip_atomic_load(xb + (3 * 2 + 1) * 128 + d, __ATOMIC_RELAXED, __HIP_MEMORY_SCOPE_AGENT);
            float vt = ((q0 + q1) + q2) + q3;
            float hf = (float)(__bf16)vt;
            htbf[d] = bfu(vt);
            htbf[128 + d] = bfu(vt - hf);
        }
        __syncthreads();
    }

    for (int t = 0; t < T_SZ; ++t) {
        const size_t tb = (size_t)(b * T_SZ + t) * DK;
        float kvn = qmat[eid[b * S_SZ + t + 1] * SKILL + SQTR * qid + sl];
        f32x2 pl[2], pg[2];
        #pragma unroll
        for (int mt = 0; mt < 2; ++mt) {
            int d0 = 16 * w + 8 * mt + 2 * quad;
            pl[mt] = *(const f32x2*)(PRE_l + tb + d0);
            pg[mt] = *(const f32x2*)(PRE_g + tb + d0);
        }
        f32x4 pf = *(const f32x4*)(PRE_f + tb + 16 * w + quad * 4);

        // ---- z-MFMA: [Wl4;Wg4] @ h~ (hi + lo) ----
        f32x4 accZ[2];
        accZ[0] = (f32x4){0.f, 0.f, 0.f, 0.f};
        accZ[1] = (f32x4){0.f, 0.f, 0.f, 0.f};
        #pragma unroll
        for (int kt = 0; kt < 4; ++kt) {
            u16x8 bh = *(const u16x8*)(htbf + 32 * kt + quad * 8);
            u16x8 bl = *(const u16x8*)(htbf + 128 + 32 * kt + quad * 8);
            #pragma unroll
            for (int mt = 0; mt < 2; ++mt) {
                accZ[mt] = mfma16(azf[mt][kt], bh, accZ[mt]);
                accZ[mt] = mfma16(azf[mt][kt], bl, accZ[mt]);
            }
        }
        #pragma unroll
        for (int mt = 0; mt < 2; ++mt) {
            u32 hpack = 0, lpack = 0;
            f32x2 fpack;
            #pragma unroll
            for (int rp = 0; rp < 2; ++rp) {
                float zl = accZ[mt][2 * rp] + pl[mt][rp];
                float zg = accZ[mt][2 * rp + 1] + pg[mt][rp];
                float LGv = sigm(zg) * (tanh_f(zl) + 1.f) * 0.5f;
                float hif = (float)(__bf16)LGv;
                hpack |= ((u32)bfu(LGv)) << (16 * rp);
                lpack |= ((u32)bfu(LGv - hif)) << (16 * rp);
                fpack[rp] = LGv;
            }
            if (l4 == 0) {
                int d0 = 16 * w + 8 * mt + 2 * quad;
                *(u32*)(LGb + d0) = hpack;
                *(u32*)(LGb + 128 + d0) = lpack;
                *(f32x2*)(LGf + d0) = fpack;
            }
        }
        __syncthreads();   // B: LG ready

        // ---- c-MFMA: Wf2 @ LG (hi+lo) ----
        {
            f32x4 accC = (f32x4){0.f, 0.f, 0.f, 0.f};
            #pragma unroll
            for (int kt = 0; kt < 4; ++kt) {
                u16x8 bh = *(const u16x8*)(LGb + 32 * kt + quad * 8);
                u16x8 bl = *(const u16x8*)(LGb + 128 + 32 * kt + quad * 8);
                accC = mfma16(acf[kt], bh, accC);
                accC = mfma16(acf[kt], bl, accC);
            }
            accC += pf;
            if (l4 == 0) *(f32x4*)(cS + 16 * w + quad * 4) = accC;
        }
        __syncthreads();   // C: c ready

        // ---- update (own quarter) ----
        float htp[16];
        #pragma unroll
        for (int mt = 0; mt < 4; ++mt) {
            int d0 = 64 * ih + 16 * mt + quad * 4;
            f32x4 lg = *(const f32x4*)(LGf + d0);
            f32x4 cc = *(const f32x4*)(cS + d0);
            f32x4 hv;
            #pragma unroll
            for (int r = 0; r < 4; ++r) {
                float f = sigm(accF[mt][r] + cc[r]);
                float hn = kvt * lg[r] + f * hreg[mt][r];
                hreg[mt][r] = hn;
                htp[mt * 4 + r] = kvn * hn;
                hv[r] = hn;
            }
            *(u16x4*)(hS + sl * RL + d0) = cvt4(hv);
        }
        #pragma unroll
        for (int mt = 0; mt < 4; ++mt)
            #pragma unroll
            for (int r = 0; r < 4; ++r)
                part[(64 * ih + 16 * mt + quad * 4 + r) * PP + jh * 16 + l4] = htp[mt * 4 + r];
        kvt = kvn;
        __syncthreads();   // E: partials + hS(t+1) ready

        // ---- reduce -> quarter-partial; publish; Zf(t+1) in gap; gather ----
        {
            int d = tid >> 2, kq = tid & 3;
            const float* pp = part + d * PP + kq * 16;
            float v = 0.f;
            #pragma unroll
            for (int i4 = 0; i4 < 4; ++i4) {
                f32x4 x = *(const f32x4*)(pp + 4 * i4);
                v += x[0] + x[1] + x[2] + x[3];
            }
            v += __shfl_xor(v, 1, 64);
            v += __shfl_xor(v, 2, 64);
            int slot = t & 1;
            if (kq == 0)
                __hip_atomic_store(xb + (qid * 2 + slot) * 128 + d, v,
                                   __ATOMIC_RELAXED, __HIP_MEMORY_SCOPE_AGENT);
            asm volatile("s_waitcnt vmcnt(0)" ::: "memory");
            if (lane == 0)
                __hip_atomic_store(flg + qid * 8 + w, t + 2,
                                   __ATOMIC_RELAXED, __HIP_MEMORY_SCOPE_AGENT);
            // Zf for t+1 hides exchange latency
            #pragma unroll
            for (int mt = 0; mt < 4; ++mt)
                accF[mt] = (f32x4){0.f, 0.f, 0.f, 0.f};
            {
                const u16* bp = hS + sl * RL + quad * 8;
                u16x8 bfr[4];
                #pragma unroll
                for (int kt = 0; kt < 4; ++kt) bfr[kt] = *(const u16x8*)(bp + kt * 32);
                #pragma unroll
                for (int mt = 0; mt < 4; ++mt)
                    #pragma unroll
                    for (int kt = 0; kt < 4; ++kt)
                        accF[mt] = mfma16(afr[mt][kt], bfr[kt], accF[mt]);
            }
            {
                int spins = 0;
                while (true) {
                    int fv = __hip_atomic_load(flg + pq * 8 + w,
                                               __ATOMIC_RELAXED, __HIP_MEMORY_SCOPE_AGENT);
                    if (__all(fv >= t + 2)) break;
                    __builtin_amdgcn_s_sleep(1);
                    if (++spins > (1 << 20)) break;
                }
            }
            asm volatile("" ::: "memory");
            if (kq == 0) {
                float q0 = (qid == 0) ? v : __hip_atomic_load(xb + (0 * 2 + slot) * 128 + d, __ATOMIC_RELAXED, __HIP_MEMORY_SCOPE_AGENT);
                float q1 = (qid == 1) ? v : __hip_atomic_load(xb + (1 * 2 + slot) * 128 + d, __ATOMIC_RELAXED, __HIP_MEMORY_SCOPE_AGENT);
                float q2 = (qid == 2) ? v : __hip_atomic_load(xb + (2 * 2 + slot) * 128 + d, __ATOMIC_RELAXED, __HIP_MEMORY_SCOPE_AGENT);
                float q3 = (qid == 3) ? v : __hip_atomic_load(xb + (3 * 2 + slot) * 128 + d, __ATOMIC_RELAXED, __HIP_MEMORY_SCOPE_AGENT);
                float vt = ((q0 + q1) + q2) + q3;
                float hf = (float)(__bf16)vt;
                htbf[d] = bfu(vt);
                htbf[128 + d] = bfu(vt - hf);
                if (qid == 0) ht_ws[tb + d] = vt;
            }
        }
        __syncthreads();   // TOP: h~ ready
    }
}

// ---------------------------------------------------------------------------
// Kernel D: pred. Weight-hoisted, NPAIR=8.
// ---------------------------------------------------------------------------
__global__ __launch_bounds__(256) void k_pred(
    const int* __restrict__ eid, const float* __restrict__ ex_t,
    const float* __restrict__ Wp, const float* __restrict__ bpv,
    const float* __restrict__ ht_ws, float* __restrict__ out)
{
    __shared__ float xS[NPAIR * 256];   // [pair][0:128 ex(t+1) | 128:256 ht]
    __shared__ int eS[NPAIR];
    const int tid = threadIdx.x;
    const int p0 = blockIdx.x * NPAIR;
    if (tid < NPAIR) {
        int p = p0 + tid;
        int b = p / T_SZ, t = p - b * T_SZ;
        eS[tid] = eid[b * S_SZ + t + 1];
    }
    __syncthreads();
    #pragma unroll
    for (int it = 0; it < 2; ++it) {
        int f = it * 256 + tid;
        int pr = f >> 6, c = f & 63;
        const float* src = (c < 32) ? ex_t + eS[pr] * DK + 4 * c
                                    : ht_ws + (size_t)(p0 + pr) * DK + 4 * (c - 32);
        *(f32x4*)(xS + pr * 256 + 4 * c) = *(const f32x4*)src;
    }
    __syncthreads();
    const int o = tid & 127, g = tid >> 7;
    const float* wr = Wp + o * 256;
    const float bias = bpv[o];
    float acc[4];
    #pragma unroll
    for (int i = 0; i < 4; ++i) acc[i] = bias;
    #pragma unroll 2
    for (int k4 = 0; k4 < 64; ++k4) {
        f32x4 w = *(const f32x4*)(wr + 4 * k4);
        #pragma unroll
        for (int i = 0; i < 4; ++i) {
            f32x4 x = *(const f32x4*)(xS + (g * 4 + i) * 256 + 4 * k4);
            acc[i] += w[0] * x[0] + w[1] * x[1] + w[2] * x[2] + w[3] * x[3];
        }
    }
    #pragma unroll
    for (int i = 0; i < 4; ++i)
        out[(size_t)(p0 + g * 4 + i) * DK + o] = sigm(acc[i]);
}

extern "C" void kernel_launch(void* const* d_in, const int* in_sizes, int n_in,
                              void* d_out, int out_size, void* d_ws, size_t ws_size,
                              hipStream_t stream) {
    const int* eid     = (const int*)d_in[0];
    const int* atime   = (const int*)d_in[1];
    const int* itime   = (const int*)d_in[2];
    const int* ansv    = (const int*)d_in[3];
    const float* qmat  = (const float*)d_in[4];
    const float* ex_t  = (const float*)d_in[5];
    const float* at_t  = (const float*)d_in[6];
    const float* it_t  = (const float*)d_in[7];
    const float* W1    = (const float*)d_in[8];
    const float* b1    = (const float*)d_in[9];
    const float* Wl    = (const float*)d_in[10];
    const float* blv   = (const float*)d_in[11];
    const float* Wg    = (const float*)d_in[12];
    const float* bgv   = (const float*)d_in[13];
    const float* Wf    = (const float*)d_in[14];
    const float* bfv   = (const float*)d_in[15];
    const float* Wp    = (const float*)d_in[16];
    const float* bpv   = (const float*)d_in[17];
    const float* h0    = (const float*)d_in[18];
    float* out = (float*)d_out;

    const size_t SZ = (size_t)B_SZ * T_SZ * DK;
    float* wsf   = (float*)d_ws;
    float* le_ws = wsf;
    float* PRE_l = wsf + SZ;
    float* PRE_g = wsf + 2 * SZ;
    float* PRE_f = wsf + 3 * SZ;
    float* ht_ws = wsf + 4 * SZ;
    // le_ws is dead after k_pre -> reuse its head for the exchange buffers.
    float* xbuf  = le_ws;                      // 32*4*2*128 f32 = 128 KiB
    int*   flags = (int*)(le_ws + 32768);      // 32*32 ints = 4 KiB

    hipFuncSetAttribute((const void*)k_main,
                        hipFuncAttributeMaxDynamicSharedMemorySize, 86016);

    dim3 gaux(508);
    k_le  <<<gaux, 256, 0, stream>>>(eid, atime, ansv, ex_t, at_t, W1, b1, le_ws);
    k_pre <<<gaux, 256, 0, stream>>>(itime, it_t, Wl, blv, Wg, bgv, Wf, bfv,
                                     le_ws, PRE_l, PRE_g, PRE_f);
    hipMemsetAsync(flags, 0, 32 * 32 * sizeof(int), stream);
    k_main<<<dim3(B_SZ, 4), 512, 86016, stream>>>(eid, qmat, Wl, Wg, Wf, h0,
                                                  PRE_l, PRE_g, PRE_f, ht_ws,
                                                  xbuf, flags);
    k_pred<<<gaux, 256, 0, stream>>>(eid, ex_t, Wp, bpv, ht_ws, out);
}

// Round 5
// 592.197 us; speedup vs baseline: 2.2494x; 1.1704x over previous
//
#include <hip/hip_runtime.h>

typedef unsigned int u32;
typedef unsigned short u16;
typedef unsigned long long u64;
typedef u16 u16x8 __attribute__((ext_vector_type(8)));
typedef u16 u16x4 __attribute__((ext_vector_type(4)));
typedef __bf16 bf16x8 __attribute__((ext_vector_type(8)));
typedef __bf16 bf16x4v __attribute__((ext_vector_type(4)));
typedef float f32x4 __attribute__((ext_vector_type(4)));
typedef float f32x2 __attribute__((ext_vector_type(2)));

#define B_SZ 32
#define S_SZ 128
#define T_SZ 127
#define DK 128
#define SKILL 256
#define SQTR 64    /* skills per block (4-way split) */
#define RL 136     /* hS row pitch (u16): 128 + 8 pad */
#define PP 68      /* part row pitch (f32): 64 + 4 pad */
#define NPAIR 8    /* (b,t) pairs per aux block; 4064 = 508*8 */
#define SPIN_CAP (1 << 18)

__device__ __forceinline__ u16x4 cvt4(f32x4 v) {
    return __builtin_bit_cast(u16x4, __builtin_convertvector(v, bf16x4v));
}
__device__ __forceinline__ u16x8 cvt8(f32x4 a, f32x4 b) {
    u16x4 x = cvt4(a), y = cvt4(b);
    u16x8 r;
    r[0]=x[0]; r[1]=x[1]; r[2]=x[2]; r[3]=x[3];
    r[4]=y[0]; r[5]=y[1]; r[6]=y[2]; r[7]=y[3];
    return r;
}
__device__ __forceinline__ u16 bfu(float x) {
    return __builtin_bit_cast(u16, (__bf16)x);
}
__device__ __forceinline__ float sigm(float x) {
    float e = __builtin_amdgcn_exp2f(-1.44269504f * x);
    return __builtin_amdgcn_rcpf(1.f + e);
}
__device__ __forceinline__ float tanh_f(float x) {
    float e = __builtin_amdgcn_exp2f(-2.88539008f * x);
    return 2.f * __builtin_amdgcn_rcpf(1.f + e) - 1.f;
}
__device__ __forceinline__ f32x4 mfma16(u16x8 a, u16x8 bb, f32x4 c) {
    return __builtin_amdgcn_mfma_f32_16x16x32_bf16(
        __builtin_bit_cast(bf16x8, a), __builtin_bit_cast(bf16x8, bb), c, 0, 0, 0);
}
__device__ __forceinline__ float pval(u64 p) {
    return __builtin_bit_cast(float, (u32)p);
}

// ---------------------------------------------------------------------------
// Kernel A: le = W1 @ [ex | at | ans] + b1. No LDS staging: x rows are
// wave-uniform (pair base via readfirstlane) -> scalar-pipe loads.
// ---------------------------------------------------------------------------
__global__ __launch_bounds__(256) void k_le(
    const int* __restrict__ eid, const int* __restrict__ atime,
    const int* __restrict__ ansv, const float* __restrict__ ex_t,
    const float* __restrict__ at_t, const float* __restrict__ W1,
    const float* __restrict__ b1, float* __restrict__ le_ws)
{
    const int tid = threadIdx.x;
    const int o = tid & 127;
    const int gi = __builtin_amdgcn_readfirstlane(tid >> 7);
    const int p0 = blockIdx.x * NPAIR + gi * 4;
    int eP[4], aP[4];
    float avP[4];
    #pragma unroll
    for (int i = 0; i < 4; ++i) {
        int p = p0 + i, b = p / T_SZ, t = p - b * T_SZ;
        int idx = b * S_SZ + t;
        eP[i] = eid[idx];
        aP[i] = atime[idx];
        avP[i] = (float)ansv[idx];
    }
    const float* wr = W1 + o * 384;
    const float bias = b1[o];
    float acc[4] = {bias, bias, bias, bias};
    #pragma unroll 4
    for (int k4 = 0; k4 < 32; ++k4) {
        f32x4 w = *(const f32x4*)(wr + 4 * k4);
        #pragma unroll
        for (int i = 0; i < 4; ++i) {
            f32x4 x = *(const f32x4*)(ex_t + eP[i] * DK + 4 * k4);
            acc[i] += w[0] * x[0] + w[1] * x[1] + w[2] * x[2] + w[3] * x[3];
        }
    }
    #pragma unroll 4
    for (int k4 = 32; k4 < 64; ++k4) {
        f32x4 w = *(const f32x4*)(wr + 4 * k4);
        #pragma unroll
        for (int i = 0; i < 4; ++i) {
            f32x4 x = *(const f32x4*)(at_t + aP[i] * DK + 4 * k4 - 128);
            acc[i] += w[0] * x[0] + w[1] * x[1] + w[2] * x[2] + w[3] * x[3];
        }
    }
    float wsum = 0.f;
    #pragma unroll 4
    for (int k4 = 64; k4 < 96; ++k4) {
        f32x4 w = *(const f32x4*)(wr + 4 * k4);
        wsum += w[0] + w[1] + w[2] + w[3];
    }
    #pragma unroll
    for (int i = 0; i < 4; ++i)
        le_ws[(p0 + i) * DK + o] = acc[i] + avP[i] * wsum;
}

// ---------------------------------------------------------------------------
// Kernel B: gate pre-activations. No LDS staging; x rows wave-uniform.
// t==0 lp handled by exact mask-multiply (w*(0*x) adds 0.0 -> bit-identical).
// ---------------------------------------------------------------------------
__global__ __launch_bounds__(256) void k_pre(
    const int* __restrict__ itime, const float* __restrict__ it_t,
    const float* __restrict__ Wl, const float* __restrict__ blv,
    const float* __restrict__ Wg, const float* __restrict__ bgv,
    const float* __restrict__ Wf, const float* __restrict__ bfv,
    const float* __restrict__ le_ws,
    float* __restrict__ PRE_l, float* __restrict__ PRE_g, float* __restrict__ PRE_f)
{
    const int tid = threadIdx.x;
    const int o = tid & 127;
    const int gi = __builtin_amdgcn_readfirstlane(tid >> 7);
    const int p0 = blockIdx.x * NPAIR + gi * 4;
    int ivP[4], lpOff[4];
    float mP[4];
    #pragma unroll
    for (int i = 0; i < 4; ++i) {
        int p = p0 + i, b = p / T_SZ, t = p - b * T_SZ;
        ivP[i] = itime[b * S_SZ + t + 1];
        mP[i] = (t == 0) ? 0.f : 1.f;
        lpOff[i] = ((t == 0) ? p : p - 1) * DK;   // masked when t==0
    }
    const float* wl = Wl + o * 512;
    const float* wg = Wg + o * 512;
    const float bl0 = blv[o], bg0 = bgv[o];
    float al[4] = {bl0, bl0, bl0, bl0};
    float ag[4] = {bg0, bg0, bg0, bg0};
    // cols 0:128 -> lp (masked)
    #pragma unroll 4
    for (int k4 = 0; k4 < 32; ++k4) {
        f32x4 w  = *(const f32x4*)(wl + 4 * k4);
        f32x4 w2 = *(const f32x4*)(wg + 4 * k4);
        #pragma unroll
        for (int i = 0; i < 4; ++i) {
            f32x4 x = *(const f32x4*)(le_ws + lpOff[i] + 4 * k4);
            #pragma unroll
            for (int j = 0; j < 4; ++j) {
                float xv = x[j] * mP[i];
                al[i] += w[j] * xv;
                ag[i] += w2[j] * xv;
            }
        }
    }
    // cols 128:256 -> it
    #pragma unroll 4
    for (int k4 = 0; k4 < 32; ++k4) {
        f32x4 w  = *(const f32x4*)(wl + 128 + 4 * k4);
        f32x4 w2 = *(const f32x4*)(wg + 128 + 4 * k4);
        #pragma unroll
        for (int i = 0; i < 4; ++i) {
            f32x4 x = *(const f32x4*)(it_t + ivP[i] * DK + 4 * k4);
            #pragma unroll
            for (int j = 0; j < 4; ++j) {
                al[i] += w[j] * x[j];
                ag[i] += w2[j] * x[j];
            }
        }
    }
    // cols 256:384 -> lc
    #pragma unroll 4
    for (int k4 = 0; k4 < 32; ++k4) {
        f32x4 w  = *(const f32x4*)(wl + 256 + 4 * k4);
        f32x4 w2 = *(const f32x4*)(wg + 256 + 4 * k4);
        #pragma unroll
        for (int i = 0; i < 4; ++i) {
            f32x4 x = *(const f32x4*)(le_ws + (p0 + i) * DK + 4 * k4);
            #pragma unroll
            for (int j = 0; j < 4; ++j) {
                al[i] += w[j] * x[j];
                ag[i] += w2[j] * x[j];
            }
        }
    }
    // f-gate: Wf cols 256:384 on it
    const float bf0 = bfv[o];
    float af[4] = {bf0, bf0, bf0, bf0};
    const float* wf = Wf + o * 384 + 256;
    #pragma unroll 4
    for (int k4 = 0; k4 < 32; ++k4) {
        f32x4 w = *(const f32x4*)(wf + 4 * k4);
        #pragma unroll
        for (int i = 0; i < 4; ++i) {
            f32x4 x = *(const f32x4*)(it_t + ivP[i] * DK + 4 * k4);
            af[i] += w[0] * x[0] + w[1] * x[1] + w[2] * x[2] + w[3] * x[3];
        }
    }
    #pragma unroll
    for (int i = 0; i < 4; ++i) {
        size_t idx = (size_t)(p0 + i) * DK + o;
        PRE_l[idx] = al[i];
        PRE_g[idx] = ag[i];
        PRE_f[idx] = af[i];
    }
}

// ---------------------------------------------------------------------------
// Kernel C: sequential scan, 4-way skill-split. Exchange via single 8-byte
// packets {u32 seq, f32 partial} per d (relaxed agent-scope u64 atomics) --
// discovery and data in ONE L2 round trip; no flags, no vmcnt fence.
// Poll is throttled (s_sleep after 64 spins) and capped (fail loud, never
// hang a harness timeout). h~ summed in canonical q0..q3 order.
// Zf(t+1) computed in the publish->poll gap (hS stable there).
// ---------------------------------------------------------------------------
__global__ __launch_bounds__(512, 1) void k_main(
    const int* __restrict__ eid, const float* __restrict__ qmat,
    const float* __restrict__ Wl, const float* __restrict__ Wg,
    const float* __restrict__ Wf, const float* __restrict__ h0,
    const float* __restrict__ PRE_l, const float* __restrict__ PRE_g,
    const float* __restrict__ PRE_f, float* __restrict__ ht_ws,
    u64* __restrict__ xbuf)
{
    extern __shared__ char smem[];
    u16*   hS   = (u16*)smem;                    // 64*136*2  = 17408
    float* part = (float*)(smem + 17408);        // 128*68*4  = 34816 -> 52224
    u16*   htbf = (u16*)(smem + 52224);          // hi[128], lo[128] -> 52736
    u16*   LGb  = (u16*)(smem + 52736);          // hi[128], lo[128] -> 53248
    float* LGf  = (float*)(smem + 53248);        // 512 -> 53760
    float* cS   = (float*)(smem + 53760);        // 512 -> 54272

    const int b    = blockIdx.x;
    const int qid  = blockIdx.y;     // skill quarter this block owns
    const int tid  = threadIdx.x;
    const int w    = tid >> 6;
    const int lane = tid & 63;
    const int quad = lane >> 4;
    const int l4   = lane & 15;
    const int ih   = w & 1;          // d-half
    const int jh   = w >> 1;         // 16-skill group within this quarter

    u64* xq = xbuf + (size_t)b * 1024;   // [qid][slot][128] u64 packets
    const int qa = (qid + 1) & 3, qb2 = (qid + 2) & 3, qc = (qid + 3) & 3;

    // ---- persistent A-frags ----
    u16x8 afr[4][4];
    #pragma unroll
    for (int mt = 0; mt < 4; ++mt)
        #pragma unroll
        for (int kt = 0; kt < 4; ++kt) {
            const float* p = Wf + (64 * ih + 16 * mt + l4) * 384 + 32 * kt + quad * 8;
            afr[mt][kt] = cvt8(*(const f32x4*)p, *(const f32x4*)(p + 4));
        }
    u16x8 azf[2][4];
    #pragma unroll
    for (int mt = 0; mt < 2; ++mt)
        #pragma unroll
        for (int kt = 0; kt < 4; ++kt) {
            int d = 16 * w + 8 * mt + (l4 >> 1);
            const float* base = (l4 & 1) ? Wg : Wl;
            const float* p = base + d * 512 + 384 + 32 * kt + quad * 8;
            azf[mt][kt] = cvt8(*(const f32x4*)p, *(const f32x4*)(p + 4));
        }
    u16x8 acf[4];
    #pragma unroll
    for (int kt = 0; kt < 4; ++kt) {
        const float* p = Wf + (16 * w + l4) * 384 + 128 + 32 * kt + quad * 8;
        acf[kt] = cvt8(*(const f32x4*)p, *(const f32x4*)(p + 4));
    }

    // ---- h0 (own quarter) -> fp32 regs + bf16 LDS mirror ----
    const int sl = 16 * jh + l4;     // local skill row 0..63
    f32x4 hreg[4];
    #pragma unroll
    for (int mt = 0; mt < 4; ++mt) {
        int d0 = 64 * ih + 16 * mt + quad * 4;
        f32x4 hv = *(const f32x4*)(h0 + (SQTR * qid + sl) * DK + d0);
        hreg[mt] = hv;
        *(u16x4*)(hS + sl * RL + d0) = cvt4(hv);
    }

    float kvt = qmat[eid[b * S_SZ] * SKILL + SQTR * qid + sl];

    f32x4 accF[4];

    // ---- prologue: partial h~0, packet exchange, Zf(t=0) ----
    {
        float htp[16];
        #pragma unroll
        for (int mt = 0; mt < 4; ++mt)
            #pragma unroll
            for (int r = 0; r < 4; ++r)
                htp[mt * 4 + r] = kvt * hreg[mt][r];
        #pragma unroll
        for (int mt = 0; mt < 4; ++mt)
            #pragma unroll
            for (int r = 0; r < 4; ++r)
                part[(64 * ih + 16 * mt + quad * 4 + r) * PP + jh * 16 + l4] = htp[mt * 4 + r];
        __syncthreads();
        int d = tid >> 2, kq = tid & 3;
        const float* pp = part + d * PP + kq * 16;
        float v = 0.f;
        #pragma unroll
        for (int i4 = 0; i4 < 4; ++i4) {
            f32x4 x = *(const f32x4*)(pp + 4 * i4);
            v += x[0] + x[1] + x[2] + x[3];
        }
        v += __shfl_xor(v, 1, 64);
        v += __shfl_xor(v, 2, 64);
        if (kq == 0) {
            u64 pkt = ((u64)1u << 32) | (u64)__builtin_bit_cast(u32, v);
            __hip_atomic_store(xq + qid * 256 + 128 + d, pkt,
                               __ATOMIC_RELAXED, __HIP_MEMORY_SCOPE_AGENT);
        }
        asm volatile("" ::: "memory");
        // Zf for t=0 overlaps partners' publish
        #pragma unroll
        for (int mt = 0; mt < 4; ++mt)
            accF[mt] = (f32x4){0.f, 0.f, 0.f, 0.f};
        {
            const u16* bp = hS + sl * RL + quad * 8;
            u16x8 bfr[4];
            #pragma unroll
            for (int kt = 0; kt < 4; ++kt) bfr[kt] = *(const u16x8*)(bp + kt * 32);
            #pragma unroll
            for (int mt = 0; mt < 4; ++mt)
                #pragma unroll
                for (int kt = 0; kt < 4; ++kt)
                    accF[mt] = mfma16(afr[mt][kt], bfr[kt], accF[mt]);
        }
        if (kq == 0) {
            u64 pa, pb, pc;
            int spins = 0;
            do {
                pa = __hip_atomic_load(xq + qa * 256 + 128 + d, __ATOMIC_RELAXED, __HIP_MEMORY_SCOPE_AGENT);
                pb = __hip_atomic_load(xq + qb2 * 256 + 128 + d, __ATOMIC_RELAXED, __HIP_MEMORY_SCOPE_AGENT);
                pc = __hip_atomic_load(xq + qc * 256 + 128 + d, __ATOMIC_RELAXED, __HIP_MEMORY_SCOPE_AGENT);
                if ((u32)(pa >> 32) >= 1u && (u32)(pb >> 32) >= 1u && (u32)(pc >> 32) >= 1u) break;
                if (spins > 64) __builtin_amdgcn_s_sleep(1);
            } while (++spins < SPIN_CAP);
            float va = pval(pa), vb = pval(pb), vc = pval(pc);
            float v0 = (qid == 0) ? v : (qid == 3) ? va : (qid == 2) ? vb : vc;
            float v1 = (qid == 1) ? v : (qid == 0) ? va : (qid == 3) ? vb : vc;
            float v2 = (qid == 2) ? v : (qid == 1) ? va : (qid == 0) ? vb : vc;
            float v3 = (qid == 3) ? v : (qid == 2) ? va : (qid == 1) ? vb : vc;
            float vt = ((v0 + v1) + v2) + v3;
            float hf = (float)(__bf16)vt;
            htbf[d] = bfu(vt);
            htbf[128 + d] = bfu(vt - hf);
        }
        __syncthreads();
    }

    for (int t = 0; t < T_SZ; ++t) {
        const size_t tb = (size_t)(b * T_SZ + t) * DK;
        float kvn = qmat[eid[b * S_SZ + t + 1] * SKILL + SQTR * qid + sl];
        f32x2 pl[2], pg[2];
        #pragma unroll
        for (int mt = 0; mt < 2; ++mt) {
            int d0 = 16 * w + 8 * mt + 2 * quad;
            pl[mt] = *(const f32x2*)(PRE_l + tb + d0);
            pg[mt] = *(const f32x2*)(PRE_g + tb + d0);
        }
        f32x4 pf = *(const f32x4*)(PRE_f + tb + 16 * w + quad * 4);

        // ---- z-MFMA: [Wl4;Wg4] @ h~ (hi + lo) ----
        f32x4 accZ[2];
        accZ[0] = (f32x4){0.f, 0.f, 0.f, 0.f};
        accZ[1] = (f32x4){0.f, 0.f, 0.f, 0.f};
        #pragma unroll
        for (int kt = 0; kt < 4; ++kt) {
            u16x8 bh = *(const u16x8*)(htbf + 32 * kt + quad * 8);
            u16x8 bl = *(const u16x8*)(htbf + 128 + 32 * kt + quad * 8);
            #pragma unroll
            for (int mt = 0; mt < 2; ++mt) {
                accZ[mt] = mfma16(azf[mt][kt], bh, accZ[mt]);
                accZ[mt] = mfma16(azf[mt][kt], bl, accZ[mt]);
            }
        }
        #pragma unroll
        for (int mt = 0; mt < 2; ++mt) {
            u32 hpack = 0, lpack = 0;
            f32x2 fpack;
            #pragma unroll
            for (int rp = 0; rp < 2; ++rp) {
                float zl = accZ[mt][2 * rp] + pl[mt][rp];
                float zg = accZ[mt][2 * rp + 1] + pg[mt][rp];
                float LGv = sigm(zg) * (tanh_f(zl) + 1.f) * 0.5f;
                float hif = (float)(__bf16)LGv;
                hpack |= ((u32)bfu(LGv)) << (16 * rp);
                lpack |= ((u32)bfu(LGv - hif)) << (16 * rp);
                fpack[rp] = LGv;
            }
            if (l4 == 0) {
                int d0 = 16 * w + 8 * mt + 2 * quad;
                *(u32*)(LGb + d0) = hpack;
                *(u32*)(LGb + 128 + d0) = lpack;
                *(f32x2*)(LGf + d0) = fpack;
            }
        }
        __syncthreads();   // B: LG ready

        // ---- c-MFMA: Wf2 @ LG (hi+lo) ----
        {
            f32x4 accC = (f32x4){0.f, 0.f, 0.f, 0.f};
            #pragma unroll
            for (int kt = 0; kt < 4; ++kt) {
                u16x8 bh = *(const u16x8*)(LGb + 32 * kt + quad * 8);
                u16x8 bl = *(const u16x8*)(LGb + 128 + 32 * kt + quad * 8);
                accC = mfma16(acf[kt], bh, accC);
                accC = mfma16(acf[kt], bl, accC);
            }
            accC += pf;
            if (l4 == 0) *(f32x4*)(cS + 16 * w + quad * 4) = accC;
        }
        __syncthreads();   // C: c ready

        // ---- update (own quarter) ----
        float htp[16];
        #pragma unroll
        for (int mt = 0; mt < 4; ++mt) {
            int d0 = 64 * ih + 16 * mt + quad * 4;
            f32x4 lg = *(const f32x4*)(LGf + d0);
            f32x4 cc = *(const f32x4*)(cS + d0);
            f32x4 hv;
            #pragma unroll
            for (int r = 0; r < 4; ++r) {
                float f = sigm(accF[mt][r] + cc[r]);
                float hn = kvt * lg[r] + f * hreg[mt][r];
                hreg[mt][r] = hn;
                htp[mt * 4 + r] = kvn * hn;
                hv[r] = hn;
            }
            *(u16x4*)(hS + sl * RL + d0) = cvt4(hv);
        }
        #pragma unroll
        for (int mt = 0; mt < 4; ++mt)
            #pragma unroll
            for (int r = 0; r < 4; ++r)
                part[(64 * ih + 16 * mt + quad * 4 + r) * PP + jh * 16 + l4] = htp[mt * 4 + r];
        kvt = kvn;
        __syncthreads();   // E: partials + hS(t+1) ready

        // ---- reduce -> quarter-partial; packet publish; Zf(t+1); poll ----
        {
            int d = tid >> 2, kq = tid & 3;
            const float* pp = part + d * PP + kq * 16;
            float v = 0.f;
            #pragma unroll
            for (int i4 = 0; i4 < 4; ++i4) {
                f32x4 x = *(const f32x4*)(pp + 4 * i4);
                v += x[0] + x[1] + x[2] + x[3];
            }
            v += __shfl_xor(v, 1, 64);
            v += __shfl_xor(v, 2, 64);
            const int slot = t & 1;            // seq = t+2
            const u32 seq = (u32)(t + 2);
            if (kq == 0) {
                u64 pkt = ((u64)seq << 32) | (u64)__builtin_bit_cast(u32, v);
                __hip_atomic_store(xq + qid * 256 + slot * 128 + d, pkt,
                                   __ATOMIC_RELAXED, __HIP_MEMORY_SCOPE_AGENT);
            }
            asm volatile("" ::: "memory");
            // Zf for t+1 hides exchange latency
            #pragma unroll
            for (int mt = 0; mt < 4; ++mt)
                accF[mt] = (f32x4){0.f, 0.f, 0.f, 0.f};
            {
                const u16* bp = hS + sl * RL + quad * 8;
                u16x8 bfr[4];
                #pragma unroll
                for (int kt = 0; kt < 4; ++kt) bfr[kt] = *(const u16x8*)(bp + kt * 32);
                #pragma unroll
                for (int mt = 0; mt < 4; ++mt)
                    #pragma unroll
                    for (int kt = 0; kt < 4; ++kt)
                        accF[mt] = mfma16(afr[mt][kt], bfr[kt], accF[mt]);
            }
            if (kq == 0) {
                u64 pa, pb, pc;
                int spins = 0;
                do {
                    pa = __hip_atomic_load(xq + qa * 256 + slot * 128 + d, __ATOMIC_RELAXED, __HIP_MEMORY_SCOPE_AGENT);
                    pb = __hip_atomic_load(xq + qb2 * 256 + slot * 128 + d, __ATOMIC_RELAXED, __HIP_MEMORY_SCOPE_AGENT);
                    pc = __hip_atomic_load(xq + qc * 256 + slot * 128 + d, __ATOMIC_RELAXED, __HIP_MEMORY_SCOPE_AGENT);
                    if ((u32)(pa >> 32) >= seq && (u32)(pb >> 32) >= seq && (u32)(pc >> 32) >= seq) break;
                    if (spins > 64) __builtin_amdgcn_s_sleep(1);
                } while (++spins < SPIN_CAP);
                float va = pval(pa), vb = pval(pb), vc = pval(pc);
                float v0 = (qid == 0) ? v : (qid == 3) ? va : (qid == 2) ? vb : vc;
                float v1 = (qid == 1) ? v : (qid == 0) ? va : (qid == 3) ? vb : vc;
                float v2 = (qid == 2) ? v : (qid == 1) ? va : (qid == 0) ? vb : vc;
                float v3 = (qid == 3) ? v : (qid == 2) ? va : (qid == 1) ? vb : vc;
                float vt = ((v0 + v1) + v2) + v3;
                float hf = (float)(__bf16)vt;
                htbf[d] = bfu(vt);
                htbf[128 + d] = bfu(vt - hf);
                if (qid == 0) ht_ws[tb + d] = vt;
            }
        }
        __syncthreads();   // TOP: h~ ready
    }
}

// ---------------------------------------------------------------------------
// Kernel D: pred. No LDS staging; x rows wave-uniform.
// ---------------------------------------------------------------------------
__global__ __launch_bounds__(256) void k_pred(
    const int* __restrict__ eid, const float* __restrict__ ex_t,
    const float* __restrict__ Wp, const float* __restrict__ bpv,
    const float* __restrict__ ht_ws, float* __restrict__ out)
{
    const int tid = threadIdx.x;
    const int o = tid & 127;
    const int gi = __builtin_amdgcn_readfirstlane(tid >> 7);
    const int p0 = blockIdx.x * NPAIR + gi * 4;
    int eP[4];
    #pragma unroll
    for (int i = 0; i < 4; ++i) {
        int p = p0 + i, b = p / T_SZ, t = p - b * T_SZ;
        eP[i] = eid[b * S_SZ + t + 1];
    }
    const float* wr = Wp + o * 256;
    const float bias = bpv[o];
    float acc[4] = {bias, bias, bias, bias};
    #pragma unroll 4
    for (int k4 = 0; k4 < 32; ++k4) {
        f32x4 w = *(const f32x4*)(wr + 4 * k4);
        #pragma unroll
        for (int i = 0; i < 4; ++i) {
            f32x4 x = *(const f32x4*)(ex_t + eP[i] * DK + 4 * k4);
            acc[i] += w[0] * x[0] + w[1] * x[1] + w[2] * x[2] + w[3] * x[3];
        }
    }
    #pragma unroll 4
    for (int k4 = 32; k4 < 64; ++k4) {
        f32x4 w = *(const f32x4*)(wr + 4 * k4);
        #pragma unroll
        for (int i = 0; i < 4; ++i) {
            f32x4 x = *(const f32x4*)(ht_ws + (size_t)(p0 + i) * DK + 4 * k4 - 128);
            acc[i] += w[0] * x[0] + w[1] * x[1] + w[2] * x[2] + w[3] * x[3];
        }
    }
    #pragma unroll
    for (int i = 0; i < 4; ++i)
        out[(size_t)(p0 + i) * DK + o] = sigm(acc[i]);
}

extern "C" void kernel_launch(void* const* d_in, const int* in_sizes, int n_in,
                              void* d_out, int out_size, void* d_ws, size_t ws_size,
                              hipStream_t stream) {
    const int* eid     = (const int*)d_in[0];
    const int* atime   = (const int*)d_in[1];
    const int* itime   = (const int*)d_in[2];
    const int* ansv    = (const int*)d_in[3];
    const float* qmat  = (const float*)d_in[4];
    const float* ex_t  = (const float*)d_in[5];
    const float* at_t  = (const float*)d_in[6];
    const float* it_t  = (const float*)d_in[7];
    const float* W1    = (const float*)d_in[8];
    const float* b1    = (const float*)d_in[9];
    const float* Wl    = (const float*)d_in[10];
    const float* blv   = (const float*)d_in[11];
    const float* Wg    = (const float*)d_in[12];
    const float* bgv   = (const float*)d_in[13];
    const float* Wf    = (const float*)d_in[14];
    const float* bfv   = (const float*)d_in[15];
    const float* Wp    = (const float*)d_in[16];
    const float* bpv   = (const float*)d_in[17];
    const float* h0    = (const float*)d_in[18];
    float* out = (float*)d_out;

    const size_t SZ = (size_t)B_SZ * T_SZ * DK;
    float* wsf   = (float*)d_ws;
    float* le_ws = wsf;
    float* PRE_l = wsf + SZ;
    float* PRE_g = wsf + 2 * SZ;
    float* PRE_f = wsf + 3 * SZ;
    float* ht_ws = wsf + 4 * SZ;
    // le_ws is dead after k_pre -> reuse its head for the packet buffer.
    u64* xbuf = (u64*)le_ws;                   // 32*4*2*128 u64 = 256 KiB

    hipFuncSetAttribute((const void*)k_main,
                        hipFuncAttributeMaxDynamicSharedMemorySize, 86016);

    dim3 gaux(508);
    k_le  <<<gaux, 256, 0, stream>>>(eid, atime, ansv, ex_t, at_t, W1, b1, le_ws);
    k_pre <<<gaux, 256, 0, stream>>>(itime, it_t, Wl, blv, Wg, bgv, Wf, bfv,
                                     le_ws, PRE_l, PRE_g, PRE_f);
    // re-arm packet buffer each replay (stale seq from prior replay otherwise)
    hipMemsetAsync(xbuf, 0, (size_t)B_SZ * 1024 * sizeof(u64), stream);
    k_main<<<dim3(B_SZ, 4), 512, 86016, stream>>>(eid, qmat, Wl, Wg, Wf, h0,
                                                  PRE_l, PRE_g, PRE_f, ht_ws,
                                                  xbuf);
    k_pred<<<gaux, 256, 0, stream>>>(eid, ex_t, Wp, bpv, ht_ws, out);
}